// Round 7
// baseline (1612.853 us; speedup 1.0000x reference)
//
#include <hip/hip_runtime.h>

// MotionTransformer: B=64,S=1024,F=136,D=64,H=2,DH=32,DFF=256,C=2
// out (FLOAT32): [logits(128) | attn(64*2*1024*1024)].
// ROUND 7: round-5 f32 pipeline with the decoded output dtype (f32, not bf16).

typedef unsigned short u16;

#define DEVI __device__ __forceinline__

// ---- 1: h = x@W_in + b_in + PE. block=row (64 thr) ----
__global__ __launch_bounds__(64) void p1_inproj(const float* __restrict__ x,
                                                const float* __restrict__ Win,
                                                const float* __restrict__ bin,
                                                float* __restrict__ hf) {
  __shared__ float xs[136];
  const int row = blockIdx.x, d = threadIdx.x;
  for (int e = d; e < 136; e += 64) xs[e] = x[(size_t)row * 136 + e];
  __syncthreads();
  float acc = 0.f;
  for (int k = 0; k < 136; ++k) acc = fmaf(xs[k], Win[(size_t)k * 64 + d], acc);
  const int s = row & 1023;
  const int m = d >> 1;
  const float freq = expf((float)(2 * m) * -0.14391156831212787f); // -ln(10000)/64
  const float ang = (float)s * freq;
  const float pe = (d & 1) ? cosf(ang) : sinf(ang);
  hf[(size_t)row * 64 + d] = acc + bin[d] + pe;
}

// ---- 2: qkv = h@W_qkv + b_qkv -> q[bh][s][32], kT[bh][32][1024], vv[bh][s][32] ----
__global__ __launch_bounds__(192) void p2_qkv(const float* __restrict__ hf,
                                              const float* __restrict__ Wq,
                                              const float* __restrict__ bq,
                                              float* __restrict__ q,
                                              float* __restrict__ kT,
                                              float* __restrict__ vv) {
  __shared__ float hr[64];
  const int row = blockIdx.x, t = threadIdx.x;
  if (t < 64) hr[t] = hf[(size_t)row * 64 + t];
  __syncthreads();
  float acc = bq[t];
  for (int k = 0; k < 64; ++k) acc = fmaf(hr[k], Wq[(size_t)k * 192 + t], acc);
  const int b = row >> 10, s = row & 1023;
  const int which = t >> 6, c = t & 63, h = c >> 5, dh = c & 31;
  const size_t bh = (size_t)(b * 2 + h);
  if (which == 0)      q[(bh * 1024 + s) * 32 + dh] = acc;
  else if (which == 1) kT[(bh * 32 + dh) * 1024 + s] = acc;
  else                 vv[(bh * 1024 + s) * 32 + dh] = acc;
}

// ---- 3: scores + softmax + attn (f32 out). block = (bh, 8 rows), 256 thr ----
__global__ __launch_bounds__(256) void p3_attn(const float* __restrict__ q,
                                               const float* __restrict__ kT,
                                               float* __restrict__ attn) {
  const int bh = blockIdx.x >> 7, i0 = (blockIdx.x & 127) * 8;
  const int t = threadIdx.x;
  __shared__ float qs[8][32];
  __shared__ float pm[8][256];
  for (int e = t; e < 256; e += 256)
    qs[e >> 5][e & 31] = q[((size_t)bh * 1024 + i0 + (e >> 5)) * 32 + (e & 31)];
  __syncthreads();
  const float scale = 0.17677669529663687f; // 1/sqrt(32)
  float sc[8][4];
#pragma unroll
  for (int r = 0; r < 8; ++r)
#pragma unroll
    for (int c = 0; c < 4; ++c) sc[r][c] = 0.f;
  for (int d = 0; d < 32; ++d) {
    float kv[4];
#pragma unroll
    for (int c = 0; c < 4; ++c) kv[c] = kT[((size_t)bh * 32 + d) * 1024 + c * 256 + t];
#pragma unroll
    for (int r = 0; r < 8; ++r) {
      const float qv = qs[r][d];
#pragma unroll
      for (int c = 0; c < 4; ++c) sc[r][c] = fmaf(qv, kv[c], sc[r][c]);
    }
  }
#pragma unroll
  for (int r = 0; r < 8; ++r)
#pragma unroll
    for (int c = 0; c < 4; ++c) sc[r][c] *= scale;
  // row max via LDS tree
#pragma unroll
  for (int r = 0; r < 8; ++r)
    pm[r][t] = fmaxf(fmaxf(sc[r][0], sc[r][1]), fmaxf(sc[r][2], sc[r][3]));
  for (int s = 128; s; s >>= 1) {
    __syncthreads();
    if (t < s) {
#pragma unroll
      for (int r = 0; r < 8; ++r) pm[r][t] = fmaxf(pm[r][t], pm[r][t + s]);
    }
  }
  __syncthreads();
  float mr[8];
#pragma unroll
  for (int r = 0; r < 8; ++r) mr[r] = pm[r][0];
  __syncthreads();
  // exp + row sum via LDS tree
#pragma unroll
  for (int r = 0; r < 8; ++r) {
    float ps = 0.f;
#pragma unroll
    for (int c = 0; c < 4; ++c) { sc[r][c] = expf(sc[r][c] - mr[r]); ps += sc[r][c]; }
    pm[r][t] = ps;
  }
  for (int s = 128; s; s >>= 1) {
    __syncthreads();
    if (t < s) {
#pragma unroll
      for (int r = 0; r < 8; ++r) pm[r][t] += pm[r][t + s];
    }
  }
  __syncthreads();
#pragma unroll
  for (int r = 0; r < 8; ++r) {
    const float inv = 1.f / pm[r][0];
    const size_t gb = ((size_t)bh * 1024 + i0 + r) * 1024;
#pragma unroll
    for (int c = 0; c < 4; ++c) attn[gb + c * 256 + t] = sc[r][c] * inv;
  }
}

// ---- 4: ctx = P@V (reads f32 attn). block = (bh, 8 rows), 256 thr ----
__global__ __launch_bounds__(256) void p4_pv(const float* __restrict__ attn,
                                             const float* __restrict__ vv,
                                             float* __restrict__ ctx) {
  const int bh = blockIdx.x >> 7, i0 = (blockIdx.x & 127) * 8;
  const int t = threadIdx.x;
  __shared__ float pr[8][1024];
  const size_t ab = ((size_t)bh * 1024 + i0) * 1024;
  for (int e = t; e < 8192; e += 256) pr[e >> 10][e & 1023] = attn[ab + e];
  __syncthreads();
  const int g = t >> 5, dh = t & 31;
  float acc = 0.f;
  for (int j = 0; j < 1024; ++j)
    acc = fmaf(pr[g][j], vv[((size_t)bh * 1024 + j) * 32 + dh], acc);
  const int b = bh >> 1, h = bh & 1;
  ctx[((size_t)b * 1024 + i0 + g) * 64 + h * 32 + dh] = acc;
}

// ---- 5: attn_out = ctx@W_o + b_o ; r1 = h + attn_out ; y1 = LN1 ----
__global__ __launch_bounds__(64) void p5_ln1(const float* __restrict__ ctx,
                                             const float* __restrict__ Wo,
                                             const float* __restrict__ bo,
                                             const float* __restrict__ hf,
                                             const float* __restrict__ g1,
                                             const float* __restrict__ be1,
                                             float* __restrict__ y1) {
  __shared__ float cr[64];
  __shared__ float st[64];
  const int row = blockIdx.x, d = threadIdx.x;
  cr[d] = ctx[(size_t)row * 64 + d];
  __syncthreads();
  float acc = bo[d];
  for (int k = 0; k < 64; ++k) acc = fmaf(cr[k], Wo[(size_t)k * 64 + d], acc);
  const float r = hf[(size_t)row * 64 + d] + acc;
  st[d] = r;
  for (int s = 32; s; s >>= 1) { __syncthreads(); if (d < s) st[d] += st[d + s]; }
  __syncthreads();
  const float mu = st[0] * (1.f / 64.f);
  __syncthreads();
  const float dd = r - mu;
  st[d] = dd * dd;
  for (int s = 32; s; s >>= 1) { __syncthreads(); if (d < s) st[d] += st[d + s]; }
  __syncthreads();
  const float var = st[0] * (1.f / 64.f);
  y1[(size_t)row * 64 + d] = dd * rsqrtf(var + 1e-5f) * g1[d] + be1[d];
}

// ---- 6: ff = relu(y1@W1+b1)@W2 + b2 ; h2 = LN2(y1 + ff) ----
__global__ __launch_bounds__(256) void p6_ff(const float* __restrict__ y1,
                                             const float* __restrict__ W1,
                                             const float* __restrict__ b1,
                                             const float* __restrict__ W2,
                                             const float* __restrict__ b2,
                                             const float* __restrict__ g2,
                                             const float* __restrict__ be2,
                                             float* __restrict__ h2) {
  __shared__ float yr[64];
  __shared__ float fr[256];
  __shared__ float part[4][64];
  __shared__ float st[64];
  const int row = blockIdx.x, t = threadIdx.x;
  if (t < 64) yr[t] = y1[(size_t)row * 64 + t];
  __syncthreads();
  float a = b1[t];
  for (int k = 0; k < 64; ++k) a = fmaf(yr[k], W1[(size_t)k * 256 + t], a);
  fr[t] = fmaxf(a, 0.f);
  __syncthreads();
  const int d = t & 63, kc = t >> 6;
  float p = 0.f;
  for (int k = 0; k < 64; ++k) {
    const int kk = kc * 64 + k;
    p = fmaf(fr[kk], W2[(size_t)kk * 64 + d], p);
  }
  part[kc][d] = p;
  __syncthreads();
  float r = 0.f;
  if (t < 64) {
    const float o2 = part[0][d] + part[1][d] + part[2][d] + part[3][d] + b2[d];
    r = yr[d] + o2;
    st[d] = r;
  }
  for (int s = 32; s; s >>= 1) { __syncthreads(); if (t < s) st[t] += st[t + s]; }
  __syncthreads();
  const float mu = st[0] * (1.f / 64.f);
  __syncthreads();
  const float dd = r - mu;
  if (t < 64) st[d] = dd * dd;
  for (int s = 32; s; s >>= 1) { __syncthreads(); if (t < s) st[t] += st[t + s]; }
  __syncthreads();
  if (t < 64) {
    const float var = st[0] * (1.f / 64.f);
    h2[(size_t)row * 64 + d] = dd * rsqrtf(var + 1e-5f) * g2[d] + be2[d];
  }
}

// ---- 7: pooled = mean_s(h2) ; logits = relu(pooled@Wc1+bc1)@Wc2 + bc2 (f32 out) ----
__global__ __launch_bounds__(256) void p7_cls(const float* __restrict__ h2,
                                              const float* __restrict__ Wc1,
                                              const float* __restrict__ bc1,
                                              const float* __restrict__ Wc2,
                                              const float* __restrict__ bc2,
                                              float* __restrict__ outp) {
  __shared__ float part[4][64];
  __shared__ float pl[64];
  __shared__ float t1s[64];
  const int b = blockIdx.x, t = threadIdx.x;
  const int d = t & 63, kc = t >> 6;
  float p = 0.f;
  for (int s = 0; s < 256; ++s) {
    const int srow = kc * 256 + s;
    p += h2[((size_t)b * 1024 + srow) * 64 + d];
  }
  part[kc][d] = p;
  __syncthreads();
  if (t < 64) {
    pl[d] = (part[0][d] + part[1][d] + part[2][d] + part[3][d]) * (1.f / 1024.f);
  }
  __syncthreads();
  if (t < 64) {
    float acc = bc1[d];
    for (int k = 0; k < 64; ++k) acc = fmaf(pl[k], Wc1[(size_t)k * 64 + d], acc);
    t1s[d] = fmaxf(acc, 0.f);
  }
  __syncthreads();
  if (t < 2) {
    float l = bc2[t];
    for (int k = 0; k < 64; ++k) l = fmaf(t1s[k], Wc2[(size_t)k * 2 + t], l);
    outp[b * 2 + t] = l;
  }
}

extern "C" void kernel_launch(void* const* d_in, const int* in_sizes, int n_in,
                              void* d_out, int out_size, void* d_ws, size_t ws_size,
                              hipStream_t stream) {
  (void)in_sizes; (void)n_in; (void)out_size; (void)ws_size;
  const float* x     = (const float*)d_in[0];
  const float* W_in  = (const float*)d_in[1];
  const float* b_in  = (const float*)d_in[2];
  const float* W_qkv = (const float*)d_in[3];
  const float* b_qkv = (const float*)d_in[4];
  const float* W_o   = (const float*)d_in[5];
  const float* b_o   = (const float*)d_in[6];
  const float* g1    = (const float*)d_in[7];
  const float* be1   = (const float*)d_in[8];
  const float* W1    = (const float*)d_in[9];
  const float* b1    = (const float*)d_in[10];
  const float* W2    = (const float*)d_in[11];
  const float* b2    = (const float*)d_in[12];
  const float* g2    = (const float*)d_in[13];
  const float* be2   = (const float*)d_in[14];
  const float* Wc1   = (const float*)d_in[15];
  const float* bc1   = (const float*)d_in[16];
  const float* Wc2   = (const float*)d_in[17];
  const float* bc2   = (const float*)d_in[18];

  char* ws = (char*)d_ws;
  const size_t SZ = (size_t)65536 * 64 * 4;   // 16.78 MB
  float* hf  = (float*)(ws + 0 * SZ);
  float* q   = (float*)(ws + 1 * SZ);
  float* kT  = (float*)(ws + 2 * SZ);
  float* vv  = (float*)(ws + 3 * SZ);
  float* ctx = (float*)(ws + 4 * SZ);
  float* y1  = (float*)(ws + 5 * SZ);
  float* h2  = (float*)(ws + 6 * SZ);

  float* outp = (float*)d_out;       // [logits 128 | attn 134217728] as f32
  float* attn = outp + 128;

  p1_inproj<<<65536, 64, 0, stream>>>(x, W_in, b_in, hf);
  p2_qkv   <<<65536, 192, 0, stream>>>(hf, W_qkv, b_qkv, q, kT, vv);
  p3_attn  <<<16384, 256, 0, stream>>>(q, kT, attn);
  p4_pv    <<<16384, 256, 0, stream>>>(attn, vv, ctx);
  p5_ln1   <<<65536, 64, 0, stream>>>(ctx, W_o, b_o, hf, g1, be1, y1);
  p6_ff    <<<65536, 256, 0, stream>>>(y1, W1, b1, W2, b2, g2, be2, h2);
  p7_cls   <<<64, 256, 0, stream>>>(h2, Wc1, bc1, Wc2, bc2, outp);
}

// Round 8
// 662.789 us; speedup vs baseline: 2.4334x; 2.4334x over previous
//
#include <hip/hip_runtime.h>

// MotionTransformer: B=64,S=1024,F=136,D=64,H=2,DH=32,DFF=256,C=2
// out (f32): [logits(128) | attn(134217728)].
// ROUND 8: fused MFMA attention (QK^T+softmax+attn-write+PV in one kernel),
// register-blocked small GEMMs (32 rows/block). Split-bf16 (hi+lo) MFMA for
// ~f32 accuracy on QK^T and PV.

typedef unsigned short u16;
typedef short bf16x8 __attribute__((ext_vector_type(8)));
typedef float f32x4 __attribute__((ext_vector_type(4)));

#define DEVI __device__ __forceinline__
#define MFMA __builtin_amdgcn_mfma_f32_16x16x32_bf16

DEVI u16 f2bf(float f) {
  union { float f; unsigned u; } v; v.f = f;
  unsigned r = v.u + 0x7FFFu + ((v.u >> 16) & 1u);
  return (u16)(r >> 16);
}
DEVI float bf2f(u16 h) {
  union { unsigned u; float f; } v; v.u = ((unsigned)h) << 16;
  return v.f;
}
DEVI float wred_sum(float v) {
#pragma unroll
  for (int off = 32; off; off >>= 1) v += __shfl_xor(v, off);
  return v;
}
DEVI float wred_max(float v) {
#pragma unroll
  for (int off = 32; off; off >>= 1) v = fmaxf(v, __shfl_xor(v, off));
  return v;
}

// ---- 1: h = x@W_in + b_in + PE. 32 rows/block, 64 thr ----
__global__ __launch_bounds__(64) void r1_inproj(const float* __restrict__ x,
                                                const float* __restrict__ Win,
                                                const float* __restrict__ bin,
                                                float* __restrict__ hf) {
  __shared__ float xs[32][140];
  const int r0 = blockIdx.x * 32, d = threadIdx.x;
  for (int e = d; e < 32 * 136; e += 64) {
    int r = e / 136, k = e - r * 136;
    xs[r][k] = x[(size_t)(r0 + r) * 136 + k];
  }
  __syncthreads();
  float acc[32];
#pragma unroll
  for (int r = 0; r < 32; ++r) acc[r] = 0.f;
  for (int k = 0; k < 136; k += 4) {
    float w0 = Win[(size_t)k * 64 + d];
    float w1 = Win[(size_t)(k + 1) * 64 + d];
    float w2 = Win[(size_t)(k + 2) * 64 + d];
    float w3 = Win[(size_t)(k + 3) * 64 + d];
#pragma unroll
    for (int r = 0; r < 32; ++r) {
      f32x4 xv = *(const f32x4*)&xs[r][k];
      acc[r] = fmaf(xv[0], w0, fmaf(xv[1], w1, fmaf(xv[2], w2, fmaf(xv[3], w3, acc[r]))));
    }
  }
  const float bcol = bin[d];
  const int m = d >> 1;
  const float freq = __expf((float)(2 * m) * -0.14391156831212787f); // -ln(1e4)/64
  const int s0 = r0 & 1023;
#pragma unroll
  for (int r = 0; r < 32; ++r) {
    const float ang = (float)(s0 + r) * freq;
    const float pe = (d & 1) ? cosf(ang) : sinf(ang);
    hf[(size_t)(r0 + r) * 64 + d] = acc[r] + bcol + pe;
  }
}

// ---- 2: qkv -> qH/qL,kH/kL [bh][s][32] bf16 ; vtH/vtL [bh][32][1024] bf16 ----
__global__ __launch_bounds__(192) void r2_qkv(const float* __restrict__ hf,
                                              const float* __restrict__ Wq,
                                              const float* __restrict__ bq,
                                              u16* __restrict__ qH, u16* __restrict__ qL,
                                              u16* __restrict__ kH, u16* __restrict__ kL,
                                              u16* __restrict__ vtH, u16* __restrict__ vtL) {
  __shared__ float hr[32][68];
  const int r0 = blockIdx.x * 32, t = threadIdx.x;
  for (int e = t; e < 2048; e += 192) {
    int r = e >> 6, k = e & 63;
    hr[r][k] = hf[(size_t)(r0 + r) * 64 + k];
  }
  __syncthreads();
  float acc[32];
  const float bias = bq[t];
#pragma unroll
  for (int r = 0; r < 32; ++r) acc[r] = bias;
  for (int k = 0; k < 64; k += 4) {
    float w0 = Wq[(size_t)k * 192 + t];
    float w1 = Wq[(size_t)(k + 1) * 192 + t];
    float w2 = Wq[(size_t)(k + 2) * 192 + t];
    float w3 = Wq[(size_t)(k + 3) * 192 + t];
#pragma unroll
    for (int r = 0; r < 32; ++r) {
      f32x4 hv = *(const f32x4*)&hr[r][k];
      acc[r] = fmaf(hv[0], w0, fmaf(hv[1], w1, fmaf(hv[2], w2, fmaf(hv[3], w3, acc[r]))));
    }
  }
  const int which = t >> 6, c = t & 63, h = c >> 5, dh = c & 31;
  const int b = r0 >> 10, s0 = r0 & 1023;
  const size_t bh = (size_t)(b * 2 + h);
#pragma unroll
  for (int r = 0; r < 32; ++r) {
    const int s = s0 + r;
    u16 hi = f2bf(acc[r]);
    u16 lo = f2bf(acc[r] - bf2f(hi));
    if (which == 0)      { qH[(bh * 1024 + s) * 32 + dh] = hi; qL[(bh * 1024 + s) * 32 + dh] = lo; }
    else if (which == 1) { kH[(bh * 1024 + s) * 32 + dh] = hi; kL[(bh * 1024 + s) * 32 + dh] = lo; }
    else                 { vtH[(bh * 32 + dh) * 1024 + s] = hi; vtL[(bh * 32 + dh) * 1024 + s] = lo; }
  }
}

// ---- 3: FUSED attention: QK^T (split MFMA) + softmax + attn write (f32) + PV (split MFMA) ----
__global__ __launch_bounds__(256) void r3_fa(const u16* __restrict__ qH, const u16* __restrict__ qL,
                                             const u16* __restrict__ kH, const u16* __restrict__ kL,
                                             const u16* __restrict__ vtH, const u16* __restrict__ vtL,
                                             float* __restrict__ attn, float* __restrict__ ctx) {
  __shared__ float sc[16][1028];        // 65.8 KB, padded (+4) for bank spread
  __shared__ float part[4][16][32];     // 8 KB PV partials
  const int bh = blockIdx.x >> 6, qt = blockIdx.x & 63;
  const int t = threadIdx.x, lane = t & 63, wv = t >> 6;
  const int fr = lane & 15, rg = lane >> 4, koff = rg * 8;
  const int i0 = qt * 16;
  const float scale = 0.17677669529663687f; // 1/sqrt(32)

  // Q fragment (rows i0..i0+15) in hi/lo
  const size_t qoff = ((size_t)bh * 1024 + i0 + fr) * 32 + koff;
  bf16x8 aqh = *(const bf16x8*)&qH[qoff];
  bf16x8 aql = *(const bf16x8*)&qL[qoff];

  // scores: 16 rows x 1024 cols
  for (int jt = wv; jt < 64; jt += 4) {
    const size_t kof = ((size_t)bh * 1024 + jt * 16 + fr) * 32 + koff;
    bf16x8 bkh = *(const bf16x8*)&kH[kof];
    bf16x8 bkl = *(const bf16x8*)&kL[kof];
    f32x4 acc = {};
    acc = MFMA(aqh, bkh, acc, 0, 0, 0);
    acc = MFMA(aqh, bkl, acc, 0, 0, 0);
    acc = MFMA(aql, bkh, acc, 0, 0, 0);
#pragma unroll
    for (int r = 0; r < 4; ++r) sc[rg * 4 + r][jt * 16 + fr] = acc[r] * scale;
  }
  __syncthreads();

  // softmax: wave wv owns rows wv*4..wv*4+3; write normalized to LDS + global
  for (int rr = 0; rr < 4; ++rr) {
    const int row = wv * 4 + rr;
    float v[16];
    float m = -1e30f;
#pragma unroll
    for (int tt = 0; tt < 16; ++tt) { v[tt] = sc[row][lane + 64 * tt]; m = fmaxf(m, v[tt]); }
    m = wred_max(m);
    float s = 0.f;
#pragma unroll
    for (int tt = 0; tt < 16; ++tt) { v[tt] = __expf(v[tt] - m); s += v[tt]; }
    s = wred_sum(s);
    const float inv = 1.f / s;
    const size_t gb = ((size_t)bh * 1024 + i0 + row) * 1024;
#pragma unroll
    for (int tt = 0; tt < 16; ++tt) {
      const float p = v[tt] * inv;
      sc[row][lane + 64 * tt] = p;
      attn[gb + lane + 64 * tt] = p;
    }
  }
  __syncthreads();

  // PV: ctx[16][32] = P @ V ; wave wv handles k-tiles wv*8..wv*8+7
  f32x4 acc2[2] = {};
  for (int i = 0; i < 8; ++i) {
    const int kt = wv * 8 + i;
    bf16x8 ph, pl;
#pragma unroll
    for (int e = 0; e < 8; ++e) {
      const float p = sc[fr][kt * 32 + koff + e];
      const u16 hi = f2bf(p);
      ph[e] = (short)hi;
      pl[e] = (short)f2bf(p - bf2f(hi));
    }
#pragma unroll
    for (int nb = 0; nb < 2; ++nb) {
      const size_t vo = ((size_t)bh * 32 + nb * 16 + fr) * 1024 + kt * 32 + koff;
      bf16x8 vh = *(const bf16x8*)&vtH[vo];
      bf16x8 vl = *(const bf16x8*)&vtL[vo];
      acc2[nb] = MFMA(ph, vh, acc2[nb], 0, 0, 0);
      acc2[nb] = MFMA(ph, vl, acc2[nb], 0, 0, 0);
      acc2[nb] = MFMA(pl, vh, acc2[nb], 0, 0, 0);
    }
  }
#pragma unroll
  for (int nb = 0; nb < 2; ++nb)
#pragma unroll
    for (int r = 0; r < 4; ++r) part[wv][rg * 4 + r][nb * 16 + fr] = acc2[nb][r];
  __syncthreads();
  const int b = bh >> 1, h = bh & 1;
  for (int e = t; e < 512; e += 256) {
    const int row = e >> 5, dh = e & 31;
    const float v = part[0][row][dh] + part[1][row][dh] + part[2][row][dh] + part[3][row][dh];
    ctx[((size_t)b * 1024 + i0 + row) * 64 + h * 32 + dh] = v;
  }
}

// ---- 5: attn_out = ctx@W_o + b_o ; r1 = h + attn_out ; y1 = LN1. 32 rows/block, 64 thr ----
__global__ __launch_bounds__(64) void r5_ln1(const float* __restrict__ ctx,
                                             const float* __restrict__ Wo,
                                             const float* __restrict__ bo,
                                             const float* __restrict__ hf,
                                             const float* __restrict__ g1,
                                             const float* __restrict__ be1,
                                             float* __restrict__ y1) {
  __shared__ float cr[32][68];
  const int r0 = blockIdx.x * 32, d = threadIdx.x;
  for (int e = d; e < 2048; e += 64) {
    int r = e >> 6, k = e & 63;
    cr[r][k] = ctx[(size_t)(r0 + r) * 64 + k];
  }
  __syncthreads();
  float acc[32];
#pragma unroll
  for (int r = 0; r < 32; ++r) acc[r] = 0.f;
  for (int k = 0; k < 64; k += 4) {
    float w0 = Wo[(size_t)k * 64 + d];
    float w1 = Wo[(size_t)(k + 1) * 64 + d];
    float w2 = Wo[(size_t)(k + 2) * 64 + d];
    float w3 = Wo[(size_t)(k + 3) * 64 + d];
#pragma unroll
    for (int r = 0; r < 32; ++r) {
      f32x4 cv = *(const f32x4*)&cr[r][k];
      acc[r] = fmaf(cv[0], w0, fmaf(cv[1], w1, fmaf(cv[2], w2, fmaf(cv[3], w3, acc[r]))));
    }
  }
  const float bias = bo[d], gd = g1[d], bd = be1[d];
  for (int r = 0; r < 32; ++r) {
    const float rr = hf[(size_t)(r0 + r) * 64 + d] + acc[r] + bias;
    const float mu = wred_sum(rr) * (1.f / 64.f);
    const float dd = rr - mu;
    const float var = wred_sum(dd * dd) * (1.f / 64.f);
    y1[(size_t)(r0 + r) * 64 + d] = dd * rsqrtf(var + 1e-5f) * gd + bd;
  }
}

// ---- 6: ff = relu(y1@W1+b1)@W2+b2 ; h2 = LN2(y1+ff). 32 rows/block, 256 thr ----
__global__ __launch_bounds__(256) void r6_ff(const float* __restrict__ y1,
                                             const float* __restrict__ W1,
                                             const float* __restrict__ b1,
                                             const float* __restrict__ W2,
                                             const float* __restrict__ b2,
                                             const float* __restrict__ g2,
                                             const float* __restrict__ be2,
                                             float* __restrict__ h2) {
  __shared__ float yr[32][68];
  __shared__ float fr[32][264];
  __shared__ float part[4][32][64];
  const int r0 = blockIdx.x * 32, t = threadIdx.x;
  for (int e = t; e < 2048; e += 256) {
    int r = e >> 6, k = e & 63;
    yr[r][k] = y1[(size_t)(r0 + r) * 64 + k];
  }
  __syncthreads();
  {
    float acc[32];
    const float bias = b1[t];
#pragma unroll
    for (int r = 0; r < 32; ++r) acc[r] = bias;
    for (int k = 0; k < 64; k += 4) {
      float w0 = W1[(size_t)k * 256 + t];
      float w1 = W1[(size_t)(k + 1) * 256 + t];
      float w2 = W1[(size_t)(k + 2) * 256 + t];
      float w3 = W1[(size_t)(k + 3) * 256 + t];
#pragma unroll
      for (int r = 0; r < 32; ++r) {
        f32x4 yv = *(const f32x4*)&yr[r][k];
        acc[r] = fmaf(yv[0], w0, fmaf(yv[1], w1, fmaf(yv[2], w2, fmaf(yv[3], w3, acc[r]))));
      }
    }
#pragma unroll
    for (int r = 0; r < 32; ++r) fr[r][t] = fmaxf(acc[r], 0.f);
  }
  __syncthreads();
  {
    const int d = t & 63, kc = t >> 6;
    float acc[32];
#pragma unroll
    for (int r = 0; r < 32; ++r) acc[r] = 0.f;
    for (int kk = 0; kk < 64; kk += 4) {
      const int k = kc * 64 + kk;
      float w0 = W2[(size_t)k * 64 + d];
      float w1 = W2[(size_t)(k + 1) * 64 + d];
      float w2 = W2[(size_t)(k + 2) * 64 + d];
      float w3 = W2[(size_t)(k + 3) * 64 + d];
#pragma unroll
      for (int r = 0; r < 32; ++r) {
        f32x4 fv = *(const f32x4*)&fr[r][k];
        acc[r] = fmaf(fv[0], w0, fmaf(fv[1], w1, fmaf(fv[2], w2, fmaf(fv[3], w3, acc[r]))));
      }
    }
#pragma unroll
    for (int r = 0; r < 32; ++r) part[kc][r][d] = acc[r];
  }
  __syncthreads();
  const int lane = t & 63, wv = t >> 6;
  const float bd2 = b2[lane], gd = g2[lane], bd = be2[lane];
  for (int rr = 0; rr < 8; ++rr) {
    const int r = wv * 8 + rr;
    const float o2 = part[0][r][lane] + part[1][r][lane] + part[2][r][lane] + part[3][r][lane] + bd2;
    const float rv = yr[r][lane] + o2;
    const float mu = wred_sum(rv) * (1.f / 64.f);
    const float dd = rv - mu;
    const float var = wred_sum(dd * dd) * (1.f / 64.f);
    h2[(size_t)(r0 + r) * 64 + lane] = dd * rsqrtf(var + 1e-5f) * gd + bd;
  }
}

// ---- 7: mean pool + classifier -> logits (f32) ----
__global__ __launch_bounds__(256) void r7_cls(const float* __restrict__ h2,
                                              const float* __restrict__ Wc1,
                                              const float* __restrict__ bc1,
                                              const float* __restrict__ Wc2,
                                              const float* __restrict__ bc2,
                                              float* __restrict__ outp) {
  __shared__ float part[4][64];
  __shared__ float pl[64];
  __shared__ float t1s[64];
  const int b = blockIdx.x, t = threadIdx.x;
  const int d = t & 63, kc = t >> 6;
  float p = 0.f;
  for (int s = 0; s < 256; ++s) {
    const int srow = kc * 256 + s;
    p += h2[((size_t)b * 1024 + srow) * 64 + d];
  }
  part[kc][d] = p;
  __syncthreads();
  if (t < 64) pl[d] = (part[0][d] + part[1][d] + part[2][d] + part[3][d]) * (1.f / 1024.f);
  __syncthreads();
  if (t < 64) {
    float acc = bc1[d];
    for (int k = 0; k < 64; ++k) acc = fmaf(pl[k], Wc1[(size_t)k * 64 + d], acc);
    t1s[d] = fmaxf(acc, 0.f);
  }
  __syncthreads();
  if (t < 2) {
    float l = bc2[t];
    for (int k = 0; k < 64; ++k) l = fmaf(t1s[k], Wc2[(size_t)k * 2 + t], l);
    outp[b * 2 + t] = l;
  }
}

extern "C" void kernel_launch(void* const* d_in, const int* in_sizes, int n_in,
                              void* d_out, int out_size, void* d_ws, size_t ws_size,
                              hipStream_t stream) {
  (void)in_sizes; (void)n_in; (void)out_size; (void)ws_size;
  const float* x     = (const float*)d_in[0];
  const float* W_in  = (const float*)d_in[1];
  const float* b_in  = (const float*)d_in[2];
  const float* W_qkv = (const float*)d_in[3];
  const float* b_qkv = (const float*)d_in[4];
  const float* W_o   = (const float*)d_in[5];
  const float* b_o   = (const float*)d_in[6];
  const float* g1    = (const float*)d_in[7];
  const float* be1   = (const float*)d_in[8];
  const float* W1    = (const float*)d_in[9];
  const float* b1    = (const float*)d_in[10];
  const float* W2    = (const float*)d_in[11];
  const float* b2    = (const float*)d_in[12];
  const float* g2    = (const float*)d_in[13];
  const float* be2   = (const float*)d_in[14];
  const float* Wc1   = (const float*)d_in[15];
  const float* bc1   = (const float*)d_in[16];
  const float* Wc2   = (const float*)d_in[17];
  const float* bc2   = (const float*)d_in[18];

  char* ws = (char*)d_ws;
  const size_t SZF = (size_t)65536 * 64 * 4;       // 16.78 MB (f32 [65536][64])
  const size_t SZH = (size_t)128 * 1024 * 32 * 2;  //  8.39 MB (bf16 [128][1024][32])
  float* hf  = (float*)(ws + 0);
  u16* qH    = (u16*)(ws + SZF);
  u16* qL    = (u16*)(ws + SZF + 1 * SZH);
  u16* kH    = (u16*)(ws + SZF + 2 * SZH);
  u16* kL    = (u16*)(ws + SZF + 3 * SZH);
  u16* vtH   = (u16*)(ws + SZF + 4 * SZH);
  u16* vtL   = (u16*)(ws + SZF + 5 * SZH);
  float* ctx = (float*)(ws + SZF + 6 * SZH);
  float* y1  = (float*)(ws + 2 * SZF + 6 * SZH);
  float* h2  = (float*)(ws + 3 * SZF + 6 * SZH);

  float* outp = (float*)d_out;       // [logits 128 | attn] f32
  float* attn = outp + 128;

  r1_inproj<<<2048, 64, 0, stream>>>(x, W_in, b_in, hf);
  r2_qkv   <<<2048, 192, 0, stream>>>(hf, W_qkv, b_qkv, qH, qL, kH, kL, vtH, vtL);
  r3_fa    <<<8192, 256, 0, stream>>>(qH, qL, kH, kL, vtH, vtL, attn, ctx);
  r5_ln1   <<<2048, 64, 0, stream>>>(ctx, W_o, b_o, hf, g1, be1, y1);
  r6_ff    <<<2048, 256, 0, stream>>>(y1, W1, b1, W2, b2, g2, be2, h2);
  r7_cls   <<<64, 256, 0, stream>>>(h2, Wc1, bc1, Wc2, bc2, outp);
}

// Round 9
// 574.646 us; speedup vs baseline: 2.8067x; 1.1534x over previous
//
#include <hip/hip_runtime.h>

// MotionTransformer: B=64,S=1024,F=136,D=64,H=2,DH=32,DFF=256,C=2
// out (f32): [logits(128) | attn(134217728)].
// ROUND 9: fa restructured for occupancy — scores in registers, split-k
// softmax across waves, bf16 P staged in swizzled 32KB LDS, 33KB total LDS
// -> 4 blocks/CU. Split-bf16 QK^T (3 MFMA); PV = P_hi x (V_hi + V_lo).

typedef unsigned short u16;
typedef short bf16x8 __attribute__((ext_vector_type(8)));
typedef float f32x4 __attribute__((ext_vector_type(4)));

#define DEVI __device__ __forceinline__
#define MFMA __builtin_amdgcn_mfma_f32_16x16x32_bf16

DEVI u16 f2bf(float f) {
  union { float f; unsigned u; } v; v.f = f;
  unsigned r = v.u + 0x7FFFu + ((v.u >> 16) & 1u);
  return (u16)(r >> 16);
}
DEVI float bf2f(u16 h) {
  union { unsigned u; float f; } v; v.u = ((unsigned)h) << 16;
  return v.f;
}
DEVI float wred_sum(float v) {
#pragma unroll
  for (int off = 32; off; off >>= 1) v += __shfl_xor(v, off);
  return v;
}

// ---- 1: h = x@W_in + b_in + PE. 32 rows/block, 64 thr ----
__global__ __launch_bounds__(64) void r1_inproj(const float* __restrict__ x,
                                                const float* __restrict__ Win,
                                                const float* __restrict__ bin,
                                                float* __restrict__ hf) {
  __shared__ float xs[32][140];
  const int r0 = blockIdx.x * 32, d = threadIdx.x;
  for (int e = d; e < 32 * 136; e += 64) {
    int r = e / 136, k = e - r * 136;
    xs[r][k] = x[(size_t)(r0 + r) * 136 + k];
  }
  __syncthreads();
  float acc[32];
#pragma unroll
  for (int r = 0; r < 32; ++r) acc[r] = 0.f;
  for (int k = 0; k < 136; k += 4) {
    float w0 = Win[(size_t)k * 64 + d];
    float w1 = Win[(size_t)(k + 1) * 64 + d];
    float w2 = Win[(size_t)(k + 2) * 64 + d];
    float w3 = Win[(size_t)(k + 3) * 64 + d];
#pragma unroll
    for (int r = 0; r < 32; ++r) {
      f32x4 xv = *(const f32x4*)&xs[r][k];
      acc[r] = fmaf(xv[0], w0, fmaf(xv[1], w1, fmaf(xv[2], w2, fmaf(xv[3], w3, acc[r]))));
    }
  }
  const float bcol = bin[d];
  const int m = d >> 1;
  const float freq = __expf((float)(2 * m) * -0.14391156831212787f); // -ln(1e4)/64
  const int s0 = r0 & 1023;
#pragma unroll
  for (int r = 0; r < 32; ++r) {
    const float ang = (float)(s0 + r) * freq;
    const float pe = (d & 1) ? cosf(ang) : sinf(ang);
    hf[(size_t)(r0 + r) * 64 + d] = acc[r] + bcol + pe;
  }
}

// ---- 2: qkv -> qH/qL,kH/kL [bh][s][32] bf16 ; vtH/vtL [bh][32][1024] bf16 ----
__global__ __launch_bounds__(192) void r2_qkv(const float* __restrict__ hf,
                                              const float* __restrict__ Wq,
                                              const float* __restrict__ bq,
                                              u16* __restrict__ qH, u16* __restrict__ qL,
                                              u16* __restrict__ kH, u16* __restrict__ kL,
                                              u16* __restrict__ vtH, u16* __restrict__ vtL) {
  __shared__ float hr[32][68];
  const int r0 = blockIdx.x * 32, t = threadIdx.x;
  for (int e = t; e < 2048; e += 192) {
    int r = e >> 6, k = e & 63;
    hr[r][k] = hf[(size_t)(r0 + r) * 64 + k];
  }
  __syncthreads();
  float acc[32];
  const float bias = bq[t];
#pragma unroll
  for (int r = 0; r < 32; ++r) acc[r] = bias;
  for (int k = 0; k < 64; k += 4) {
    float w0 = Wq[(size_t)k * 192 + t];
    float w1 = Wq[(size_t)(k + 1) * 192 + t];
    float w2 = Wq[(size_t)(k + 2) * 192 + t];
    float w3 = Wq[(size_t)(k + 3) * 192 + t];
#pragma unroll
    for (int r = 0; r < 32; ++r) {
      f32x4 hv = *(const f32x4*)&hr[r][k];
      acc[r] = fmaf(hv[0], w0, fmaf(hv[1], w1, fmaf(hv[2], w2, fmaf(hv[3], w3, acc[r]))));
    }
  }
  const int which = t >> 6, c = t & 63, h = c >> 5, dh = c & 31;
  const int b = r0 >> 10, s0 = r0 & 1023;
  const size_t bh = (size_t)(b * 2 + h);
#pragma unroll
  for (int r = 0; r < 32; ++r) {
    const int s = s0 + r;
    u16 hi = f2bf(acc[r]);
    u16 lo = f2bf(acc[r] - bf2f(hi));
    if (which == 0)      { qH[(bh * 1024 + s) * 32 + dh] = hi; qL[(bh * 1024 + s) * 32 + dh] = lo; }
    else if (which == 1) { kH[(bh * 1024 + s) * 32 + dh] = hi; kL[(bh * 1024 + s) * 32 + dh] = lo; }
    else                 { vtH[(bh * 32 + dh) * 1024 + s] = hi; vtL[(bh * 32 + dh) * 1024 + s] = lo; }
  }
}

// ---- 3: FUSED attention, register-resident scores, 33KB LDS ----
__global__ __launch_bounds__(256, 4) void r3_fa(const u16* __restrict__ qH, const u16* __restrict__ qL,
                                                const u16* __restrict__ kH, const u16* __restrict__ kL,
                                                const u16* __restrict__ vtH, const u16* __restrict__ vtL,
                                                float* __restrict__ attn, float* __restrict__ ctx) {
  __shared__ __align__(16) char smem[33792];
  u16* pb = (u16*)smem;                        // [16][1024] bf16 P, swizzled (32 KB)
  float* redm = (float*)(smem + 32768);        // [4][16]
  float* reds = (float*)(smem + 33280);        // [4][16]
  float* part = (float*)smem;                  // [4][16][32] aliased over pb after PV

  const int bh = blockIdx.x >> 6, qt = blockIdx.x & 63;
  const int t = threadIdx.x, lane = t & 63, wv = t >> 6;
  const int fr = lane & 15, rg = lane >> 4, koff = rg * 8;
  const int i0 = qt * 16;
  const float scale = 0.17677669529663687f; // 1/sqrt(32)

  // Q fragments (rows i0..i0+15), hi/lo
  const size_t qoff = ((size_t)bh * 1024 + i0 + fr) * 32 + koff;
  bf16x8 aqh = *(const bf16x8*)&qH[qoff];
  bf16x8 aql = *(const bf16x8*)&qL[qoff];

  // QK^T: wave wv owns k-cols [wv*256, wv*256+256) for all 16 rows.
  f32x4 s[16];
#pragma unroll
  for (int jl = 0; jl < 16; ++jl) {
    const int jt = wv * 16 + jl;
    const size_t kof = ((size_t)bh * 1024 + jt * 16 + fr) * 32 + koff;
    bf16x8 bkh = *(const bf16x8*)&kH[kof];
    bf16x8 bkl = *(const bf16x8*)&kL[kof];
    f32x4 a = {};
    a = MFMA(aqh, bkh, a, 0, 0, 0);
    a = MFMA(aqh, bkl, a, 0, 0, 0);
    a = MFMA(aql, bkh, a, 0, 0, 0);
#pragma unroll
    for (int r = 0; r < 4; ++r) s[jl][r] = a[r] * scale;
  }

  // split-k softmax: local max -> 16-lane reduce -> LDS exchange across waves
  float m4[4];
#pragma unroll
  for (int r = 0; r < 4; ++r) m4[r] = s[0][r];
#pragma unroll
  for (int jl = 1; jl < 16; ++jl)
#pragma unroll
    for (int r = 0; r < 4; ++r) m4[r] = fmaxf(m4[r], s[jl][r]);
#pragma unroll
  for (int off = 1; off < 16; off <<= 1)
#pragma unroll
    for (int r = 0; r < 4; ++r) m4[r] = fmaxf(m4[r], __shfl_xor(m4[r], off));
  if (fr == 0) {
#pragma unroll
    for (int r = 0; r < 4; ++r) redm[wv * 16 + rg * 4 + r] = m4[r];
  }
  __syncthreads();
  float mg[4];
#pragma unroll
  for (int r = 0; r < 4; ++r) {
    const int row = rg * 4 + r;
    mg[r] = fmaxf(fmaxf(redm[row], redm[16 + row]), fmaxf(redm[32 + row], redm[48 + row]));
  }
  float s4[4] = {0.f, 0.f, 0.f, 0.f};
#pragma unroll
  for (int jl = 0; jl < 16; ++jl)
#pragma unroll
    for (int r = 0; r < 4; ++r) { s[jl][r] = __expf(s[jl][r] - mg[r]); s4[r] += s[jl][r]; }
#pragma unroll
  for (int off = 1; off < 16; off <<= 1)
#pragma unroll
    for (int r = 0; r < 4; ++r) s4[r] += __shfl_xor(s4[r], off);
  if (fr == 0) {
#pragma unroll
    for (int r = 0; r < 4; ++r) reds[wv * 16 + rg * 4 + r] = s4[r];
  }
  __syncthreads();
  float inv[4];
#pragma unroll
  for (int r = 0; r < 4; ++r) {
    const int row = rg * 4 + r;
    inv[r] = 1.f / (reds[row] + reds[16 + row] + reds[32 + row] + reds[48 + row]);
  }

  // p: write f32 attn (global) + bf16 pb (LDS, swizzled col ^ (rg<<4))
#pragma unroll
  for (int r = 0; r < 4; ++r) {
    const int row = rg * 4 + r;
    const size_t gb = ((size_t)bh * 1024 + i0 + row) * 1024;
    const int sw = rg << 4;
    const int rb = row * 1024;
#pragma unroll
    for (int jl = 0; jl < 16; ++jl) {
      const int col = (wv * 16 + jl) * 16 + fr;
      const float p = s[jl][r] * inv[r];
      attn[gb + col] = p;
      pb[rb + (col ^ sw)] = f2bf(p);
    }
  }
  __syncthreads();

  // PV: wave wv handles k-tiles wv*8..wv*8+7. A-frag row=fr, k-elems rg*8.
  const int sw2 = (fr >> 2) << 4;
  f32x4 acc2[2] = {};
#pragma unroll
  for (int i = 0; i < 8; ++i) {
    const int kt = wv * 8 + i;
    const int cb = kt * 32 + rg * 8;
    bf16x8 ph = *(const bf16x8*)&pb[fr * 1024 + (cb ^ sw2)];
#pragma unroll
    for (int nb = 0; nb < 2; ++nb) {
      const size_t vo = ((size_t)bh * 32 + nb * 16 + fr) * 1024 + cb;
      bf16x8 vh = *(const bf16x8*)&vtH[vo];
      bf16x8 vl = *(const bf16x8*)&vtL[vo];
      acc2[nb] = MFMA(ph, vh, acc2[nb], 0, 0, 0);
      acc2[nb] = MFMA(ph, vl, acc2[nb], 0, 0, 0);
    }
  }
  __syncthreads();   // all pb reads done; part may overwrite
#pragma unroll
  for (int nb = 0; nb < 2; ++nb)
#pragma unroll
    for (int r = 0; r < 4; ++r)
      part[(wv * 16 + rg * 4 + r) * 32 + nb * 16 + fr] = acc2[nb][r];
  __syncthreads();
  const int b = bh >> 1, h = bh & 1;
  for (int e = t; e < 512; e += 256) {
    const int row = e >> 5, dh = e & 31;
    const float v = part[row * 32 + dh] + part[512 + row * 32 + dh] +
                    part[1024 + row * 32 + dh] + part[1536 + row * 32 + dh];
    ctx[((size_t)b * 1024 + i0 + row) * 64 + h * 32 + dh] = v;
  }
}

// ---- 5: attn_out = ctx@W_o + b_o ; r1 = h + attn_out ; y1 = LN1. 4 waves ----
__global__ __launch_bounds__(256) void r5_ln1(const float* __restrict__ ctx,
                                              const float* __restrict__ Wo,
                                              const float* __restrict__ bo,
                                              const float* __restrict__ hf,
                                              const float* __restrict__ g1,
                                              const float* __restrict__ be1,
                                              float* __restrict__ y1) {
  __shared__ float cr[32][68];
  __shared__ float wo[64][64];
  const int r0 = blockIdx.x * 32, t = threadIdx.x, lane = t & 63, wv = t >> 6;
  for (int e = t; e < 2048; e += 256) cr[e >> 6][e & 63] = ctx[(size_t)(r0 + (e >> 6)) * 64 + (e & 63)];
  for (int e = t; e < 4096; e += 256) wo[e >> 6][e & 63] = Wo[e];
  __syncthreads();
  const int d = lane;
  const float bias = bo[d], gd = g1[d], bd = be1[d];
  const int rbase = wv * 8;
  float acc[8];
#pragma unroll
  for (int rr = 0; rr < 8; ++rr) acc[rr] = bias;
  for (int k = 0; k < 64; ++k) {
    const float w = wo[k][d];
#pragma unroll
    for (int rr = 0; rr < 8; ++rr) acc[rr] = fmaf(cr[rbase + rr][k], w, acc[rr]);
  }
  for (int rr = 0; rr < 8; ++rr) {
    const int r = rbase + rr;
    const float rv = hf[(size_t)(r0 + r) * 64 + d] + acc[rr];
    const float mu = wred_sum(rv) * (1.f / 64.f);
    const float dd = rv - mu;
    const float var = wred_sum(dd * dd) * (1.f / 64.f);
    y1[(size_t)(r0 + r) * 64 + d] = dd * rsqrtf(var + 1e-5f) * gd + bd;
  }
}

// ---- 6: ff = relu(y1@W1+b1)@W2+b2 ; h2 = LN2(y1+ff). 32 rows/block, 256 thr ----
__global__ __launch_bounds__(256) void r6_ff(const float* __restrict__ y1,
                                             const float* __restrict__ W1,
                                             const float* __restrict__ b1,
                                             const float* __restrict__ W2,
                                             const float* __restrict__ b2,
                                             const float* __restrict__ g2,
                                             const float* __restrict__ be2,
                                             float* __restrict__ h2) {
  __shared__ float yr[32][68];
  __shared__ float fr[32][264];
  __shared__ float part[4][32][64];
  const int r0 = blockIdx.x * 32, t = threadIdx.x;
  for (int e = t; e < 2048; e += 256) {
    int r = e >> 6, k = e & 63;
    yr[r][k] = y1[(size_t)(r0 + r) * 64 + k];
  }
  __syncthreads();
  {
    float acc[32];
    const float bias = b1[t];
#pragma unroll
    for (int r = 0; r < 32; ++r) acc[r] = bias;
    for (int k = 0; k < 64; k += 4) {
      float w0 = W1[(size_t)k * 256 + t];
      float w1 = W1[(size_t)(k + 1) * 256 + t];
      float w2 = W1[(size_t)(k + 2) * 256 + t];
      float w3 = W1[(size_t)(k + 3) * 256 + t];
#pragma unroll
      for (int r = 0; r < 32; ++r) {
        f32x4 yv = *(const f32x4*)&yr[r][k];
        acc[r] = fmaf(yv[0], w0, fmaf(yv[1], w1, fmaf(yv[2], w2, fmaf(yv[3], w3, acc[r]))));
      }
    }
#pragma unroll
    for (int r = 0; r < 32; ++r) fr[r][t] = fmaxf(acc[r], 0.f);
  }
  __syncthreads();
  {
    const int d = t & 63, kc = t >> 6;
    float acc[32];
#pragma unroll
    for (int r = 0; r < 32; ++r) acc[r] = 0.f;
    for (int kk = 0; kk < 64; kk += 4) {
      const int k = kc * 64 + kk;
      float w0 = W2[(size_t)k * 64 + d];
      float w1 = W2[(size_t)(k + 1) * 64 + d];
      float w2 = W2[(size_t)(k + 2) * 64 + d];
      float w3 = W2[(size_t)(k + 3) * 64 + d];
#pragma unroll
      for (int r = 0; r < 32; ++r) {
        f32x4 fv = *(const f32x4*)&fr[r][k];
        acc[r] = fmaf(fv[0], w0, fmaf(fv[1], w1, fmaf(fv[2], w2, fmaf(fv[3], w3, acc[r]))));
      }
    }
#pragma unroll
    for (int r = 0; r < 32; ++r) part[kc][r][d] = acc[r];
  }
  __syncthreads();
  const int lane = t & 63, wv = t >> 6;
  const float bd2 = b2[lane], gd = g2[lane], bd = be2[lane];
  for (int rr = 0; rr < 8; ++rr) {
    const int r = wv * 8 + rr;
    const float o2 = part[0][r][lane] + part[1][r][lane] + part[2][r][lane] + part[3][r][lane] + bd2;
    const float rv = yr[r][lane] + o2;
    const float mu = wred_sum(rv) * (1.f / 64.f);
    const float dd = rv - mu;
    const float var = wred_sum(dd * dd) * (1.f / 64.f);
    h2[(size_t)(r0 + r) * 64 + lane] = dd * rsqrtf(var + 1e-5f) * gd + bd;
  }
}

// ---- 7: mean pool + classifier -> logits (f32) ----
__global__ __launch_bounds__(256) void r7_cls(const float* __restrict__ h2,
                                              const float* __restrict__ Wc1,
                                              const float* __restrict__ bc1,
                                              const float* __restrict__ Wc2,
                                              const float* __restrict__ bc2,
                                              float* __restrict__ outp) {
  __shared__ float part[4][64];
  __shared__ float pl[64];
  __shared__ float t1s[64];
  const int b = blockIdx.x, t = threadIdx.x;
  const int d = t & 63, kc = t >> 6;
  float p = 0.f;
  for (int s = 0; s < 256; ++s) {
    const int srow = kc * 256 + s;
    p += h2[((size_t)b * 1024 + srow) * 64 + d];
  }
  part[kc][d] = p;
  __syncthreads();
  if (t < 64) pl[d] = (part[0][d] + part[1][d] + part[2][d] + part[3][d]) * (1.f / 1024.f);
  __syncthreads();
  if (t < 64) {
    float acc = bc1[d];
    for (int k = 0; k < 64; ++k) acc = fmaf(pl[k], Wc1[(size_t)k * 64 + d], acc);
    t1s[d] = fmaxf(acc, 0.f);
  }
  __syncthreads();
  if (t < 2) {
    float l = bc2[t];
    for (int k = 0; k < 64; ++k) l = fmaf(t1s[k], Wc2[(size_t)k * 2 + t], l);
    outp[b * 2 + t] = l;
  }
}

extern "C" void kernel_launch(void* const* d_in, const int* in_sizes, int n_in,
                              void* d_out, int out_size, void* d_ws, size_t ws_size,
                              hipStream_t stream) {
  (void)in_sizes; (void)n_in; (void)out_size; (void)ws_size;
  const float* x     = (const float*)d_in[0];
  const float* W_in  = (const float*)d_in[1];
  const float* b_in  = (const float*)d_in[2];
  const float* W_qkv = (const float*)d_in[3];
  const float* b_qkv = (const float*)d_in[4];
  const float* W_o   = (const float*)d_in[5];
  const float* b_o   = (const float*)d_in[6];
  const float* g1    = (const float*)d_in[7];
  const float* be1   = (const float*)d_in[8];
  const float* W1    = (const float*)d_in[9];
  const float* b1    = (const float*)d_in[10];
  const float* W2    = (const float*)d_in[11];
  const float* b2    = (const float*)d_in[12];
  const float* g2    = (const float*)d_in[13];
  const float* be2   = (const float*)d_in[14];
  const float* Wc1   = (const float*)d_in[15];
  const float* bc1   = (const float*)d_in[16];
  const float* Wc2   = (const float*)d_in[17];
  const float* bc2   = (const float*)d_in[18];

  char* ws = (char*)d_ws;
  const size_t SZF = (size_t)65536 * 64 * 4;       // 16.78 MB (f32 [65536][64])
  const size_t SZH = (size_t)128 * 1024 * 32 * 2;  //  8.39 MB (bf16 [128][1024][32])
  float* hf  = (float*)(ws + 0);
  u16* qH    = (u16*)(ws + SZF);
  u16* qL    = (u16*)(ws + SZF + 1 * SZH);
  u16* kH    = (u16*)(ws + SZF + 2 * SZH);
  u16* kL    = (u16*)(ws + SZF + 3 * SZH);
  u16* vtH   = (u16*)(ws + SZF + 4 * SZH);
  u16* vtL   = (u16*)(ws + SZF + 5 * SZH);
  float* ctx = (float*)(ws + SZF + 6 * SZH);
  float* y1  = (float*)(ws + 2 * SZF + 6 * SZH);
  float* h2  = (float*)(ws + 3 * SZF + 6 * SZH);

  float* outp = (float*)d_out;       // [logits 128 | attn] f32
  float* attn = outp + 128;

  r1_inproj<<<2048, 64, 0, stream>>>(x, W_in, b_in, hf);
  r2_qkv   <<<2048, 192, 0, stream>>>(hf, W_qkv, b_qkv, qH, qL, kH, kL, vtH, vtL);
  r3_fa    <<<8192, 256, 0, stream>>>(qH, qL, kH, kL, vtH, vtL, attn, ctx);
  r5_ln1   <<<2048, 256, 0, stream>>>(ctx, W_o, b_o, hf, g1, be1, y1);
  r6_ff    <<<2048, 256, 0, stream>>>(y1, W1, b1, W2, b2, g2, be2, h2);
  r7_cls   <<<64, 256, 0, stream>>>(h2, Wc1, bc1, Wc2, bc2, outp);
}

// Round 10
// 532.807 us; speedup vs baseline: 3.0271x; 1.0785x over previous
//
#include <hip/hip_runtime.h>

// MotionTransformer: B=64,S=1024,F=136,D=64,H=2,DH=32,DFF=256,C=2
// out (f32): [logits(128) | attn(134217728)].
// ROUND 10: fa attn-write coalesced via LDS bf16 P; r2 V-transpose through
// LDS; r6 at 16 rows/block for 4 blocks/CU.

typedef unsigned short u16;
typedef short bf16x8 __attribute__((ext_vector_type(8)));
typedef short bf16x4 __attribute__((ext_vector_type(4)));
typedef float f32x4 __attribute__((ext_vector_type(4)));

#define DEVI __device__ __forceinline__
#define MFMA __builtin_amdgcn_mfma_f32_16x16x32_bf16

DEVI u16 f2bf(float f) {
  union { float f; unsigned u; } v; v.f = f;
  unsigned r = v.u + 0x7FFFu + ((v.u >> 16) & 1u);
  return (u16)(r >> 16);
}
DEVI float bf2f(u16 h) {
  union { unsigned u; float f; } v; v.u = ((unsigned)h) << 16;
  return v.f;
}
DEVI float wred_sum(float v) {
#pragma unroll
  for (int off = 32; off; off >>= 1) v += __shfl_xor(v, off);
  return v;
}

// ---- 1: h = x@W_in + b_in + PE. 32 rows/block, 64 thr ----
__global__ __launch_bounds__(64) void r1_inproj(const float* __restrict__ x,
                                                const float* __restrict__ Win,
                                                const float* __restrict__ bin,
                                                float* __restrict__ hf) {
  __shared__ float xs[32][140];
  const int r0 = blockIdx.x * 32, d = threadIdx.x;
  for (int e = d; e < 32 * 136; e += 64) {
    int r = e / 136, k = e - r * 136;
    xs[r][k] = x[(size_t)(r0 + r) * 136 + k];
  }
  __syncthreads();
  float acc[32];
#pragma unroll
  for (int r = 0; r < 32; ++r) acc[r] = 0.f;
  for (int k = 0; k < 136; k += 4) {
    float w0 = Win[(size_t)k * 64 + d];
    float w1 = Win[(size_t)(k + 1) * 64 + d];
    float w2 = Win[(size_t)(k + 2) * 64 + d];
    float w3 = Win[(size_t)(k + 3) * 64 + d];
#pragma unroll
    for (int r = 0; r < 32; ++r) {
      f32x4 xv = *(const f32x4*)&xs[r][k];
      acc[r] = fmaf(xv[0], w0, fmaf(xv[1], w1, fmaf(xv[2], w2, fmaf(xv[3], w3, acc[r]))));
    }
  }
  const float bcol = bin[d];
  const int m = d >> 1;
  const float freq = __expf((float)(2 * m) * -0.14391156831212787f); // -ln(1e4)/64
  const int s0 = r0 & 1023;
#pragma unroll
  for (int r = 0; r < 32; ++r) {
    const float ang = (float)(s0 + r) * freq;
    const float pe = (d & 1) ? cosf(ang) : sinf(ang);
    hf[(size_t)(r0 + r) * 64 + d] = acc[r] + bcol + pe;
  }
}

// ---- 2: qkv -> qH/qL,kH/kL [bh][s][32] ; vtH/vtL [bh][32][1024] (LDS transpose) ----
__global__ __launch_bounds__(192) void r2_qkv(const float* __restrict__ hf,
                                              const float* __restrict__ Wq,
                                              const float* __restrict__ bq,
                                              u16* __restrict__ qH, u16* __restrict__ qL,
                                              u16* __restrict__ kH, u16* __restrict__ kL,
                                              u16* __restrict__ vtH, u16* __restrict__ vtL) {
  __shared__ float hr[32][68];
  __shared__ u16 vbH[64][40];   // [h*32+dh][r], pad 40 for banks+align
  __shared__ u16 vbL[64][40];
  const int r0 = blockIdx.x * 32, t = threadIdx.x;
  for (int e = t; e < 2048; e += 192) {
    int r = e >> 6, k = e & 63;
    hr[r][k] = hf[(size_t)(r0 + r) * 64 + k];
  }
  __syncthreads();
  float acc[32];
  const float bias = bq[t];
#pragma unroll
  for (int r = 0; r < 32; ++r) acc[r] = bias;
  for (int k = 0; k < 64; k += 4) {
    float w0 = Wq[(size_t)k * 192 + t];
    float w1 = Wq[(size_t)(k + 1) * 192 + t];
    float w2 = Wq[(size_t)(k + 2) * 192 + t];
    float w3 = Wq[(size_t)(k + 3) * 192 + t];
#pragma unroll
    for (int r = 0; r < 32; ++r) {
      f32x4 hv = *(const f32x4*)&hr[r][k];
      acc[r] = fmaf(hv[0], w0, fmaf(hv[1], w1, fmaf(hv[2], w2, fmaf(hv[3], w3, acc[r]))));
    }
  }
  const int which = t >> 6, c = t & 63, h = c >> 5, dh = c & 31;
  const int b = r0 >> 10, s0 = r0 & 1023;
  const size_t bh = (size_t)(b * 2 + h);
#pragma unroll
  for (int r = 0; r < 32; ++r) {
    const int s = s0 + r;
    u16 hi = f2bf(acc[r]);
    u16 lo = f2bf(acc[r] - bf2f(hi));
    if (which == 0)      { qH[(bh * 1024 + s) * 32 + dh] = hi; qL[(bh * 1024 + s) * 32 + dh] = lo; }
    else if (which == 1) { kH[(bh * 1024 + s) * 32 + dh] = hi; kL[(bh * 1024 + s) * 32 + dh] = lo; }
    else                 { vbH[c][r] = hi; vbL[c][r] = lo; }
  }
  __syncthreads();
  // coalesced v^T writeout: thread owns one (h,dh) row of 32 s-values (64B)
  if (t < 128) {
    const int hh = (t & 63) >> 5, dh2 = t & 31;
    const size_t vb = ((size_t)(b * 2 + hh) * 32 + dh2) * 1024 + s0;
    const u16* src = (t < 64) ? &vbH[(t & 63)][0] : &vbL[(t & 63)][0];
    u16* dst = (t < 64) ? vtH : vtL;
#pragma unroll
    for (int i = 0; i < 2; ++i) {
      bf16x8 v = *(const bf16x8*)&src[i * 16];
      bf16x8 w = *(const bf16x8*)&src[i * 16 + 8];
      *(bf16x8*)&dst[vb + i * 16] = v;
      *(bf16x8*)&dst[vb + i * 16 + 8] = w;
    }
  }
}

// ---- 3: FUSED attention; coalesced attn write from LDS bf16 P ----
__global__ __launch_bounds__(256, 4) void r3_fa(const u16* __restrict__ qH, const u16* __restrict__ qL,
                                                const u16* __restrict__ kH, const u16* __restrict__ kL,
                                                const u16* __restrict__ vtH, const u16* __restrict__ vtL,
                                                float* __restrict__ attn, float* __restrict__ ctx) {
  __shared__ __align__(16) char smem[33280];
  u16* pb = (u16*)smem;                        // [16][1024] bf16 P, swizzled (32 KB)
  float* redm = (float*)(smem + 32768);        // [64]
  float* reds = (float*)(smem + 33024);        // [64]
  float* part = (float*)smem;                  // [4][16][32] aliased over pb after PV

  const int bh = blockIdx.x >> 6, qt = blockIdx.x & 63;
  const int t = threadIdx.x, lane = t & 63, wv = t >> 6;
  const int fr = lane & 15, rg = lane >> 4, koff = rg * 8;
  const int i0 = qt * 16;
  const float scale = 0.17677669529663687f; // 1/sqrt(32)

  const size_t qoff = ((size_t)bh * 1024 + i0 + fr) * 32 + koff;
  bf16x8 aqh = *(const bf16x8*)&qH[qoff];
  bf16x8 aql = *(const bf16x8*)&qL[qoff];

  // QK^T: wave wv owns k-cols [wv*256, wv*256+256)
  f32x4 s[16];
#pragma unroll
  for (int jl = 0; jl < 16; ++jl) {
    const int jt = wv * 16 + jl;
    const size_t kof = ((size_t)bh * 1024 + jt * 16 + fr) * 32 + koff;
    bf16x8 bkh = *(const bf16x8*)&kH[kof];
    bf16x8 bkl = *(const bf16x8*)&kL[kof];
    f32x4 a = {};
    a = MFMA(aqh, bkh, a, 0, 0, 0);
    a = MFMA(aqh, bkl, a, 0, 0, 0);
    a = MFMA(aql, bkh, a, 0, 0, 0);
#pragma unroll
    for (int r = 0; r < 4; ++r) s[jl][r] = a[r] * scale;
  }

  // split-k softmax
  float m4[4];
#pragma unroll
  for (int r = 0; r < 4; ++r) m4[r] = s[0][r];
#pragma unroll
  for (int jl = 1; jl < 16; ++jl)
#pragma unroll
    for (int r = 0; r < 4; ++r) m4[r] = fmaxf(m4[r], s[jl][r]);
#pragma unroll
  for (int off = 1; off < 16; off <<= 1)
#pragma unroll
    for (int r = 0; r < 4; ++r) m4[r] = fmaxf(m4[r], __shfl_xor(m4[r], off));
  if (fr == 0) {
#pragma unroll
    for (int r = 0; r < 4; ++r) redm[wv * 16 + rg * 4 + r] = m4[r];
  }
  __syncthreads();
  float mg[4];
#pragma unroll
  for (int r = 0; r < 4; ++r) {
    const int row = rg * 4 + r;
    mg[r] = fmaxf(fmaxf(redm[row], redm[16 + row]), fmaxf(redm[32 + row], redm[48 + row]));
  }
  float s4[4] = {0.f, 0.f, 0.f, 0.f};
#pragma unroll
  for (int jl = 0; jl < 16; ++jl)
#pragma unroll
    for (int r = 0; r < 4; ++r) { s[jl][r] = __expf(s[jl][r] - mg[r]); s4[r] += s[jl][r]; }
#pragma unroll
  for (int off = 1; off < 16; off <<= 1)
#pragma unroll
    for (int r = 0; r < 4; ++r) s4[r] += __shfl_xor(s4[r], off);
  if (fr == 0) {
#pragma unroll
    for (int r = 0; r < 4; ++r) reds[wv * 16 + rg * 4 + r] = s4[r];
  }
  __syncthreads();
  float inv[4];
#pragma unroll
  for (int r = 0; r < 4; ++r) {
    const int row = rg * 4 + r;
    inv[r] = 1.f / (reds[row] + reds[16 + row] + reds[32 + row] + reds[48 + row]);
  }

  // P -> bf16 LDS (swizzled: col ^ ((row>>2)<<4))
#pragma unroll
  for (int r = 0; r < 4; ++r) {
    const int row = rg * 4 + r;
    const int sw = rg << 4;
    const int rb = row * 1024;
#pragma unroll
    for (int jl = 0; jl < 16; ++jl) {
      const int col = (wv * 16 + jl) * 16 + fr;
      pb[rb + (col ^ sw)] = f2bf(s[jl][r] * inv[r]);
    }
  }
  __syncthreads();

  // coalesced attn write: thread t owns row t>>4, col chunks (t&15)*8 + 128c
  {
    const int row = t >> 4, x16 = t & 15;
    const int sw = (row >> 2) << 4;
    const size_t gb = ((size_t)bh * 1024 + i0 + row) * 1024;
#pragma unroll
    for (int c = 0; c < 8; ++c) {
      const int col = x16 * 8 + 128 * c;
      bf16x8 v = *(const bf16x8*)&pb[row * 1024 + (col ^ sw)];
      f32x4 lo, hi;
#pragma unroll
      for (int i = 0; i < 4; ++i) { lo[i] = bf2f((u16)v[i]); hi[i] = bf2f((u16)v[4 + i]); }
      *(f32x4*)&attn[gb + col] = lo;
      *(f32x4*)&attn[gb + col + 4] = hi;
    }
  }

  // PV: wave wv handles k-tiles wv*8..wv*8+7
  const int sw2 = (fr >> 2) << 4;
  f32x4 acc2[2] = {};
#pragma unroll
  for (int i = 0; i < 8; ++i) {
    const int kt = wv * 8 + i;
    const int cb = kt * 32 + rg * 8;
    bf16x8 ph = *(const bf16x8*)&pb[fr * 1024 + (cb ^ sw2)];
#pragma unroll
    for (int nb = 0; nb < 2; ++nb) {
      const size_t vo = ((size_t)bh * 32 + nb * 16 + fr) * 1024 + cb;
      bf16x8 vh = *(const bf16x8*)&vtH[vo];
      bf16x8 vl = *(const bf16x8*)&vtL[vo];
      acc2[nb] = MFMA(ph, vh, acc2[nb], 0, 0, 0);
      acc2[nb] = MFMA(ph, vl, acc2[nb], 0, 0, 0);
    }
  }
  __syncthreads();   // all pb reads done; part may overwrite
#pragma unroll
  for (int nb = 0; nb < 2; ++nb)
#pragma unroll
    for (int r = 0; r < 4; ++r)
      part[(wv * 16 + rg * 4 + r) * 32 + nb * 16 + fr] = acc2[nb][r];
  __syncthreads();
  const int b = bh >> 1, h = bh & 1;
  for (int e = t; e < 512; e += 256) {
    const int row = e >> 5, dh = e & 31;
    const float v = part[row * 32 + dh] + part[512 + row * 32 + dh] +
                    part[1024 + row * 32 + dh] + part[1536 + row * 32 + dh];
    ctx[((size_t)b * 1024 + i0 + row) * 64 + h * 32 + dh] = v;
  }
}

// ---- 5: attn_out = ctx@W_o + b_o ; r1 = h + attn_out ; y1 = LN1. 4 waves ----
__global__ __launch_bounds__(256) void r5_ln1(const float* __restrict__ ctx,
                                              const float* __restrict__ Wo,
                                              const float* __restrict__ bo,
                                              const float* __restrict__ hf,
                                              const float* __restrict__ g1,
                                              const float* __restrict__ be1,
                                              float* __restrict__ y1) {
  __shared__ float cr[32][68];
  __shared__ float wo[64][64];
  const int r0 = blockIdx.x * 32, t = threadIdx.x, lane = t & 63, wv = t >> 6;
  for (int e = t; e < 2048; e += 256) cr[e >> 6][e & 63] = ctx[(size_t)(r0 + (e >> 6)) * 64 + (e & 63)];
  for (int e = t; e < 4096; e += 256) wo[e >> 6][e & 63] = Wo[e];
  __syncthreads();
  const int d = lane;
  const float bias = bo[d], gd = g1[d], bd = be1[d];
  const int rbase = wv * 8;
  float acc[8];
#pragma unroll
  for (int rr = 0; rr < 8; ++rr) acc[rr] = bias;
  for (int k = 0; k < 64; ++k) {
    const float w = wo[k][d];
#pragma unroll
    for (int rr = 0; rr < 8; ++rr) acc[rr] = fmaf(cr[rbase + rr][k], w, acc[rr]);
  }
  for (int rr = 0; rr < 8; ++rr) {
    const int r = rbase + rr;
    const float rv = hf[(size_t)(r0 + r) * 64 + d] + acc[rr];
    const float mu = wred_sum(rv) * (1.f / 64.f);
    const float dd = rv - mu;
    const float var = wred_sum(dd * dd) * (1.f / 64.f);
    y1[(size_t)(r0 + r) * 64 + d] = dd * rsqrtf(var + 1e-5f) * gd + bd;
  }
}

// ---- 6: ff = relu(y1@W1+b1)@W2+b2 ; h2 = LN2(y1+ff). 16 rows/block ----
__global__ __launch_bounds__(256) void r6_ff(const float* __restrict__ y1,
                                             const float* __restrict__ W1,
                                             const float* __restrict__ b1,
                                             const float* __restrict__ W2,
                                             const float* __restrict__ b2,
                                             const float* __restrict__ g2,
                                             const float* __restrict__ be2,
                                             float* __restrict__ h2) {
  __shared__ float yr[16][68];
  __shared__ float fr[16][264];
  __shared__ float part[4][16][64];
  const int r0 = blockIdx.x * 16, t = threadIdx.x;
  for (int e = t; e < 1024; e += 256) {
    int r = e >> 6, k = e & 63;
    yr[r][k] = y1[(size_t)(r0 + r) * 64 + k];
  }
  __syncthreads();
  {
    float acc[16];
    const float bias = b1[t];
#pragma unroll
    for (int r = 0; r < 16; ++r) acc[r] = bias;
    for (int k = 0; k < 64; k += 4) {
      float w0 = W1[(size_t)k * 256 + t];
      float w1 = W1[(size_t)(k + 1) * 256 + t];
      float w2 = W1[(size_t)(k + 2) * 256 + t];
      float w3 = W1[(size_t)(k + 3) * 256 + t];
#pragma unroll
      for (int r = 0; r < 16; ++r) {
        f32x4 yv = *(const f32x4*)&yr[r][k];
        acc[r] = fmaf(yv[0], w0, fmaf(yv[1], w1, fmaf(yv[2], w2, fmaf(yv[3], w3, acc[r]))));
      }
    }
#pragma unroll
    for (int r = 0; r < 16; ++r) fr[r][t] = fmaxf(acc[r], 0.f);
  }
  __syncthreads();
  {
    const int d = t & 63, kc = t >> 6;
    float acc[16];
#pragma unroll
    for (int r = 0; r < 16; ++r) acc[r] = 0.f;
    for (int kk = 0; kk < 64; kk += 4) {
      const int k = kc * 64 + kk;
      float w0 = W2[(size_t)k * 64 + d];
      float w1 = W2[(size_t)(k + 1) * 64 + d];
      float w2 = W2[(size_t)(k + 2) * 64 + d];
      float w3 = W2[(size_t)(k + 3) * 64 + d];
#pragma unroll
      for (int r = 0; r < 16; ++r) {
        f32x4 fv = *(const f32x4*)&fr[r][k];
        acc[r] = fmaf(fv[0], w0, fmaf(fv[1], w1, fmaf(fv[2], w2, fmaf(fv[3], w3, acc[r]))));
      }
    }
#pragma unroll
    for (int r = 0; r < 16; ++r) part[kc][r][d] = acc[r];
  }
  __syncthreads();
  const int lane = t & 63, wv = t >> 6;
  const float bd2 = b2[lane], gd = g2[lane], bd = be2[lane];
  for (int rr = 0; rr < 4; ++rr) {
    const int r = wv * 4 + rr;
    const float o2 = part[0][r][lane] + part[1][r][lane] + part[2][r][lane] + part[3][r][lane] + bd2;
    const float rv = yr[r][lane] + o2;
    const float mu = wred_sum(rv) * (1.f / 64.f);
    const float dd = rv - mu;
    const float var = wred_sum(dd * dd) * (1.f / 64.f);
    h2[(size_t)(r0 + r) * 64 + lane] = dd * rsqrtf(var + 1e-5f) * gd + bd;
  }
}

// ---- 7: mean pool + classifier -> logits (f32) ----
__global__ __launch_bounds__(256) void r7_cls(const float* __restrict__ h2,
                                              const float* __restrict__ Wc1,
                                              const float* __restrict__ bc1,
                                              const float* __restrict__ Wc2,
                                              const float* __restrict__ bc2,
                                              float* __restrict__ outp) {
  __shared__ float part[4][64];
  __shared__ float pl[64];
  __shared__ float t1s[64];
  const int b = blockIdx.x, t = threadIdx.x;
  const int d = t & 63, kc = t >> 6;
  float p = 0.f;
  for (int s = 0; s < 256; ++s) {
    const int srow = kc * 256 + s;
    p += h2[((size_t)b * 1024 + srow) * 64 + d];
  }
  part[kc][d] = p;
  __syncthreads();
  if (t < 64) pl[d] = (part[0][d] + part[1][d] + part[2][d] + part[3][d]) * (1.f / 1024.f);
  __syncthreads();
  if (t < 64) {
    float acc = bc1[d];
    for (int k = 0; k < 64; ++k) acc = fmaf(pl[k], Wc1[(size_t)k * 64 + d], acc);
    t1s[d] = fmaxf(acc, 0.f);
  }
  __syncthreads();
  if (t < 2) {
    float l = bc2[t];
    for (int k = 0; k < 64; ++k) l = fmaf(t1s[k], Wc2[(size_t)k * 2 + t], l);
    outp[b * 2 + t] = l;
  }
}

extern "C" void kernel_launch(void* const* d_in, const int* in_sizes, int n_in,
                              void* d_out, int out_size, void* d_ws, size_t ws_size,
                              hipStream_t stream) {
  (void)in_sizes; (void)n_in; (void)out_size; (void)ws_size;
  const float* x     = (const float*)d_in[0];
  const float* W_in  = (const float*)d_in[1];
  const float* b_in  = (const float*)d_in[2];
  const float* W_qkv = (const float*)d_in[3];
  const float* b_qkv = (const float*)d_in[4];
  const float* W_o   = (const float*)d_in[5];
  const float* b_o   = (const float*)d_in[6];
  const float* g1    = (const float*)d_in[7];
  const float* be1   = (const float*)d_in[8];
  const float* W1    = (const float*)d_in[9];
  const float* b1    = (const float*)d_in[10];
  const float* W2    = (const float*)d_in[11];
  const float* b2    = (const float*)d_in[12];
  const float* g2    = (const float*)d_in[13];
  const float* be2   = (const float*)d_in[14];
  const float* Wc1   = (const float*)d_in[15];
  const float* bc1   = (const float*)d_in[16];
  const float* Wc2   = (const float*)d_in[17];
  const float* bc2   = (const float*)d_in[18];

  char* ws = (char*)d_ws;
  const size_t SZF = (size_t)65536 * 64 * 4;       // 16.78 MB
  const size_t SZH = (size_t)128 * 1024 * 32 * 2;  //  8.39 MB
  float* hf  = (float*)(ws + 0);
  u16* qH    = (u16*)(ws + SZF);
  u16* qL    = (u16*)(ws + SZF + 1 * SZH);
  u16* kH    = (u16*)(ws + SZF + 2 * SZH);
  u16* kL    = (u16*)(ws + SZF + 3 * SZH);
  u16* vtH   = (u16*)(ws + SZF + 4 * SZH);
  u16* vtL   = (u16*)(ws + SZF + 5 * SZH);
  float* ctx = (float*)(ws + SZF + 6 * SZH);
  float* y1  = (float*)(ws + 2 * SZF + 6 * SZH);
  float* h2  = (float*)(ws + 3 * SZF + 6 * SZH);

  float* outp = (float*)d_out;       // [logits 128 | attn] f32
  float* attn = outp + 128;

  r1_inproj<<<2048, 64, 0, stream>>>(x, W_in, b_in, hf);
  r2_qkv   <<<2048, 192, 0, stream>>>(hf, W_qkv, b_qkv, qH, qL, kH, kL, vtH, vtL);
  r3_fa    <<<8192, 256, 0, stream>>>(qH, qL, kH, kL, vtH, vtL, attn, ctx);
  r5_ln1   <<<2048, 256, 0, stream>>>(ctx, W_o, b_o, hf, g1, be1, y1);
  r6_ff    <<<4096, 256, 0, stream>>>(y1, W1, b1, W2, b2, g2, be2, h2);
  r7_cls   <<<64, 256, 0, stream>>>(h2, Wc1, bc1, Wc2, bc2, outp);
}

// Round 11
// 494.403 us; speedup vs baseline: 3.2622x; 1.0777x over previous
//
#include <hip/hip_runtime.h>

// MotionTransformer: B=64,S=1024,F=136,D=64,H=2,DH=32,DFF=256,C=2
// out (f32): [logits(128) | attn(134217728)].
// ROUND 11: post-attention chain fused into one kernel (no y1/h2 HBM
// round-trips, hierarchical pooling); fa attn stores non-temporal.

typedef unsigned short u16;
typedef short bf16x8 __attribute__((ext_vector_type(8)));
typedef float f32x4 __attribute__((ext_vector_type(4)));

#define DEVI __device__ __forceinline__
#define MFMA __builtin_amdgcn_mfma_f32_16x16x32_bf16

DEVI u16 f2bf(float f) {
  union { float f; unsigned u; } v; v.f = f;
  unsigned r = v.u + 0x7FFFu + ((v.u >> 16) & 1u);
  return (u16)(r >> 16);
}
DEVI float bf2f(u16 h) {
  union { unsigned u; float f; } v; v.u = ((unsigned)h) << 16;
  return v.f;
}
DEVI float wred_sum(float v) {
#pragma unroll
  for (int off = 32; off; off >>= 1) v += __shfl_xor(v, off);
  return v;
}

// ---- 1: h = x@W_in + b_in + PE. 32 rows/block, 64 thr ----
__global__ __launch_bounds__(64) void r1_inproj(const float* __restrict__ x,
                                                const float* __restrict__ Win,
                                                const float* __restrict__ bin,
                                                float* __restrict__ hf) {
  __shared__ float xs[32][140];
  const int r0 = blockIdx.x * 32, d = threadIdx.x;
  for (int e = d; e < 32 * 136; e += 64) {
    int r = e / 136, k = e - r * 136;
    xs[r][k] = x[(size_t)(r0 + r) * 136 + k];
  }
  __syncthreads();
  float acc[32];
#pragma unroll
  for (int r = 0; r < 32; ++r) acc[r] = 0.f;
  for (int k = 0; k < 136; k += 4) {
    float w0 = Win[(size_t)k * 64 + d];
    float w1 = Win[(size_t)(k + 1) * 64 + d];
    float w2 = Win[(size_t)(k + 2) * 64 + d];
    float w3 = Win[(size_t)(k + 3) * 64 + d];
#pragma unroll
    for (int r = 0; r < 32; ++r) {
      f32x4 xv = *(const f32x4*)&xs[r][k];
      acc[r] = fmaf(xv[0], w0, fmaf(xv[1], w1, fmaf(xv[2], w2, fmaf(xv[3], w3, acc[r]))));
    }
  }
  const float bcol = bin[d];
  const int m = d >> 1;
  const float freq = __expf((float)(2 * m) * -0.14391156831212787f); // -ln(1e4)/64
  const int s0 = r0 & 1023;
#pragma unroll
  for (int r = 0; r < 32; ++r) {
    const float ang = (float)(s0 + r) * freq;
    const float pe = (d & 1) ? cosf(ang) : sinf(ang);
    hf[(size_t)(r0 + r) * 64 + d] = acc[r] + bcol + pe;
  }
}

// ---- 2: qkv -> qH/qL,kH/kL [bh][s][32] ; vtH/vtL [bh][32][1024] (LDS transpose) ----
__global__ __launch_bounds__(192) void r2_qkv(const float* __restrict__ hf,
                                              const float* __restrict__ Wq,
                                              const float* __restrict__ bq,
                                              u16* __restrict__ qH, u16* __restrict__ qL,
                                              u16* __restrict__ kH, u16* __restrict__ kL,
                                              u16* __restrict__ vtH, u16* __restrict__ vtL) {
  __shared__ float hr[32][68];
  __shared__ u16 vbH[64][40];
  __shared__ u16 vbL[64][40];
  const int r0 = blockIdx.x * 32, t = threadIdx.x;
  for (int e = t; e < 2048; e += 192) {
    int r = e >> 6, k = e & 63;
    hr[r][k] = hf[(size_t)(r0 + r) * 64 + k];
  }
  __syncthreads();
  float acc[32];
  const float bias = bq[t];
#pragma unroll
  for (int r = 0; r < 32; ++r) acc[r] = bias;
  for (int k = 0; k < 64; k += 4) {
    float w0 = Wq[(size_t)k * 192 + t];
    float w1 = Wq[(size_t)(k + 1) * 192 + t];
    float w2 = Wq[(size_t)(k + 2) * 192 + t];
    float w3 = Wq[(size_t)(k + 3) * 192 + t];
#pragma unroll
    for (int r = 0; r < 32; ++r) {
      f32x4 hv = *(const f32x4*)&hr[r][k];
      acc[r] = fmaf(hv[0], w0, fmaf(hv[1], w1, fmaf(hv[2], w2, fmaf(hv[3], w3, acc[r]))));
    }
  }
  const int which = t >> 6, c = t & 63, h = c >> 5, dh = c & 31;
  const int b = r0 >> 10, s0 = r0 & 1023;
  const size_t bh = (size_t)(b * 2 + h);
#pragma unroll
  for (int r = 0; r < 32; ++r) {
    const int s = s0 + r;
    u16 hi = f2bf(acc[r]);
    u16 lo = f2bf(acc[r] - bf2f(hi));
    if (which == 0)      { qH[(bh * 1024 + s) * 32 + dh] = hi; qL[(bh * 1024 + s) * 32 + dh] = lo; }
    else if (which == 1) { kH[(bh * 1024 + s) * 32 + dh] = hi; kL[(bh * 1024 + s) * 32 + dh] = lo; }
    else                 { vbH[c][r] = hi; vbL[c][r] = lo; }
  }
  __syncthreads();
  if (t < 128) {
    const int hh = (t & 63) >> 5, dh2 = t & 31;
    const size_t vb = ((size_t)(b * 2 + hh) * 32 + dh2) * 1024 + s0;
    const u16* src = (t < 64) ? &vbH[(t & 63)][0] : &vbL[(t & 63)][0];
    u16* dst = (t < 64) ? vtH : vtL;
#pragma unroll
    for (int i = 0; i < 2; ++i) {
      bf16x8 v = *(const bf16x8*)&src[i * 16];
      bf16x8 w = *(const bf16x8*)&src[i * 16 + 8];
      *(bf16x8*)&dst[vb + i * 16] = v;
      *(bf16x8*)&dst[vb + i * 16 + 8] = w;
    }
  }
}

// ---- 3: FUSED attention; nt attn stores ----
__global__ __launch_bounds__(256, 4) void r3_fa(const u16* __restrict__ qH, const u16* __restrict__ qL,
                                                const u16* __restrict__ kH, const u16* __restrict__ kL,
                                                const u16* __restrict__ vtH, const u16* __restrict__ vtL,
                                                float* __restrict__ attn, float* __restrict__ ctx) {
  __shared__ __align__(16) char smem[33280];
  u16* pb = (u16*)smem;                        // [16][1024] bf16 P, swizzled (32 KB)
  float* redm = (float*)(smem + 32768);
  float* reds = (float*)(smem + 33024);
  float* part = (float*)smem;                  // aliased over pb after PV

  const int bh = blockIdx.x >> 6, qt = blockIdx.x & 63;
  const int t = threadIdx.x, lane = t & 63, wv = t >> 6;
  const int fr = lane & 15, rg = lane >> 4, koff = rg * 8;
  const int i0 = qt * 16;
  const float scale = 0.17677669529663687f; // 1/sqrt(32)

  const size_t qoff = ((size_t)bh * 1024 + i0 + fr) * 32 + koff;
  bf16x8 aqh = *(const bf16x8*)&qH[qoff];
  bf16x8 aql = *(const bf16x8*)&qL[qoff];

  f32x4 s[16];
#pragma unroll
  for (int jl = 0; jl < 16; ++jl) {
    const int jt = wv * 16 + jl;
    const size_t kof = ((size_t)bh * 1024 + jt * 16 + fr) * 32 + koff;
    bf16x8 bkh = *(const bf16x8*)&kH[kof];
    bf16x8 bkl = *(const bf16x8*)&kL[kof];
    f32x4 a = {};
    a = MFMA(aqh, bkh, a, 0, 0, 0);
    a = MFMA(aqh, bkl, a, 0, 0, 0);
    a = MFMA(aql, bkh, a, 0, 0, 0);
#pragma unroll
    for (int r = 0; r < 4; ++r) s[jl][r] = a[r] * scale;
  }

  float m4[4];
#pragma unroll
  for (int r = 0; r < 4; ++r) m4[r] = s[0][r];
#pragma unroll
  for (int jl = 1; jl < 16; ++jl)
#pragma unroll
    for (int r = 0; r < 4; ++r) m4[r] = fmaxf(m4[r], s[jl][r]);
#pragma unroll
  for (int off = 1; off < 16; off <<= 1)
#pragma unroll
    for (int r = 0; r < 4; ++r) m4[r] = fmaxf(m4[r], __shfl_xor(m4[r], off));
  if (fr == 0) {
#pragma unroll
    for (int r = 0; r < 4; ++r) redm[wv * 16 + rg * 4 + r] = m4[r];
  }
  __syncthreads();
  float mg[4];
#pragma unroll
  for (int r = 0; r < 4; ++r) {
    const int row = rg * 4 + r;
    mg[r] = fmaxf(fmaxf(redm[row], redm[16 + row]), fmaxf(redm[32 + row], redm[48 + row]));
  }
  float s4[4] = {0.f, 0.f, 0.f, 0.f};
#pragma unroll
  for (int jl = 0; jl < 16; ++jl)
#pragma unroll
    for (int r = 0; r < 4; ++r) { s[jl][r] = __expf(s[jl][r] - mg[r]); s4[r] += s[jl][r]; }
#pragma unroll
  for (int off = 1; off < 16; off <<= 1)
#pragma unroll
    for (int r = 0; r < 4; ++r) s4[r] += __shfl_xor(s4[r], off);
  if (fr == 0) {
#pragma unroll
    for (int r = 0; r < 4; ++r) reds[wv * 16 + rg * 4 + r] = s4[r];
  }
  __syncthreads();
  float inv[4];
#pragma unroll
  for (int r = 0; r < 4; ++r) {
    const int row = rg * 4 + r;
    inv[r] = 1.f / (reds[row] + reds[16 + row] + reds[32 + row] + reds[48 + row]);
  }

#pragma unroll
  for (int r = 0; r < 4; ++r) {
    const int row = rg * 4 + r;
    const int sw = rg << 4;
    const int rb = row * 1024;
#pragma unroll
    for (int jl = 0; jl < 16; ++jl) {
      const int col = (wv * 16 + jl) * 16 + fr;
      pb[rb + (col ^ sw)] = f2bf(s[jl][r] * inv[r]);
    }
  }
  __syncthreads();

  // coalesced nt attn write from LDS
  {
    const int row = t >> 4, x16 = t & 15;
    const int sw = (row >> 2) << 4;
    const size_t gb = ((size_t)bh * 1024 + i0 + row) * 1024;
#pragma unroll
    for (int c = 0; c < 8; ++c) {
      const int col = x16 * 8 + 128 * c;
      bf16x8 v = *(const bf16x8*)&pb[row * 1024 + (col ^ sw)];
      f32x4 lo, hi;
#pragma unroll
      for (int i = 0; i < 4; ++i) { lo[i] = bf2f((u16)v[i]); hi[i] = bf2f((u16)v[4 + i]); }
      __builtin_nontemporal_store(lo, (f32x4*)&attn[gb + col]);
      __builtin_nontemporal_store(hi, (f32x4*)&attn[gb + col + 4]);
    }
  }

  // PV
  const int sw2 = (fr >> 2) << 4;
  f32x4 acc2[2] = {};
#pragma unroll
  for (int i = 0; i < 8; ++i) {
    const int kt = wv * 8 + i;
    const int cb = kt * 32 + rg * 8;
    bf16x8 ph = *(const bf16x8*)&pb[fr * 1024 + (cb ^ sw2)];
#pragma unroll
    for (int nb = 0; nb < 2; ++nb) {
      const size_t vo = ((size_t)bh * 32 + nb * 16 + fr) * 1024 + cb;
      bf16x8 vh = *(const bf16x8*)&vtH[vo];
      bf16x8 vl = *(const bf16x8*)&vtL[vo];
      acc2[nb] = MFMA(ph, vh, acc2[nb], 0, 0, 0);
      acc2[nb] = MFMA(ph, vl, acc2[nb], 0, 0, 0);
    }
  }
  __syncthreads();
#pragma unroll
  for (int nb = 0; nb < 2; ++nb)
#pragma unroll
    for (int r = 0; r < 4; ++r)
      part[(wv * 16 + rg * 4 + r) * 32 + nb * 16 + fr] = acc2[nb][r];
  __syncthreads();
  const int b = bh >> 1, h = bh & 1;
  for (int e = t; e < 512; e += 256) {
    const int row = e >> 5, dh = e & 31;
    const float v = part[row * 32 + dh] + part[512 + row * 32 + dh] +
                    part[1024 + row * 32 + dh] + part[1536 + row * 32 + dh];
    ctx[((size_t)b * 1024 + i0 + row) * 64 + h * 32 + dh] = v;
  }
}

// ---- 4: FUSED ln1 + FF + ln2 + partial pool. 16 rows/block, 256 thr, 37.8KB LDS ----
__global__ __launch_bounds__(256) void r56_ln_ff(const float* __restrict__ ctx,
                                                 const float* __restrict__ Wo,
                                                 const float* __restrict__ bo,
                                                 const float* __restrict__ hf,
                                                 const float* __restrict__ g1,
                                                 const float* __restrict__ be1,
                                                 const float* __restrict__ W1,
                                                 const float* __restrict__ b1,
                                                 const float* __restrict__ W2,
                                                 const float* __restrict__ b2,
                                                 const float* __restrict__ g2,
                                                 const float* __restrict__ be2,
                                                 float* __restrict__ pp) {
  __shared__ __align__(16) char smem[38656];
  float* yr   = (float*)smem;                 // [16][68]          0..4352
  float* fr   = (float*)(smem + 4352);        // [16][264]      4352..21248 (phase B/C)
  float* part = (float*)(smem + 21248);       // [4][16][64]   21248..37632 (phase C/D)
  float* cr   = (float*)(smem + 4352);        // [16][68] phase A (alias fr)
  float* wo   = (float*)(smem + 8704);        // [64][64] phase A (alias fr/part tail)
  float* pw   = (float*)(smem + 37632);       // [4][64]
  const int r0 = blockIdx.x * 16;
  const int t = threadIdx.x, d = t & 63, wv = t >> 6;

  for (int e = t; e < 1024; e += 256) cr[(e >> 6) * 68 + (e & 63)] = ctx[(size_t)(r0 + (e >> 6)) * 64 + (e & 63)];
  for (int e = t; e < 4096; e += 256) wo[e] = Wo[e];
  __syncthreads();

  // phase A: attn_out = ctx@Wo + bo ; r1 = hf + attn_out ; y1 = LN1 -> yr
  {
    float acc[4];
    const float bias = bo[d];
#pragma unroll
    for (int r = 0; r < 4; ++r) acc[r] = bias;
    for (int k = 0; k < 64; ++k) {
      const float w = wo[k * 64 + d];
#pragma unroll
      for (int r = 0; r < 4; ++r) acc[r] = fmaf(cr[(wv * 4 + r) * 68 + k], w, acc[r]);
    }
    const float gd = g1[d], bd = be1[d];
#pragma unroll
    for (int r = 0; r < 4; ++r) {
      const int row = wv * 4 + r;
      const float rv = hf[(size_t)(r0 + row) * 64 + d] + acc[r];
      const float mu = wred_sum(rv) * (1.f / 64.f);
      const float dd = rv - mu;
      const float var = wred_sum(dd * dd) * (1.f / 64.f);
      yr[row * 68 + d] = dd * rsqrtf(var + 1e-5f) * gd + bd;
    }
  }
  __syncthreads();

  // phase B: f = relu(y1@W1 + b1) -> fr ; thread t owns col t (256 cols)
  {
    float acc[16];
    const float bias = b1[t];
#pragma unroll
    for (int r = 0; r < 16; ++r) acc[r] = bias;
    for (int k = 0; k < 64; k += 4) {
      float w0 = W1[(size_t)k * 256 + t];
      float w1 = W1[(size_t)(k + 1) * 256 + t];
      float w2 = W1[(size_t)(k + 2) * 256 + t];
      float w3 = W1[(size_t)(k + 3) * 256 + t];
#pragma unroll
      for (int r = 0; r < 16; ++r) {
        f32x4 yv = *(const f32x4*)&yr[r * 68 + k];
        acc[r] = fmaf(yv[0], w0, fmaf(yv[1], w1, fmaf(yv[2], w2, fmaf(yv[3], w3, acc[r]))));
      }
    }
#pragma unroll
    for (int r = 0; r < 16; ++r) fr[r * 264 + t] = fmaxf(acc[r], 0.f);
  }
  __syncthreads();

  // phase C: o2 partials = f@W2 ; kc = wv covers k in [kc*64, kc*64+64)
  {
    float acc[16];
#pragma unroll
    for (int r = 0; r < 16; ++r) acc[r] = 0.f;
    for (int kk = 0; kk < 64; kk += 4) {
      const int k = wv * 64 + kk;
      float w0 = W2[(size_t)k * 64 + d];
      float w1 = W2[(size_t)(k + 1) * 64 + d];
      float w2 = W2[(size_t)(k + 2) * 64 + d];
      float w3 = W2[(size_t)(k + 3) * 64 + d];
#pragma unroll
      for (int r = 0; r < 16; ++r) {
        f32x4 fv = *(const f32x4*)&fr[r * 264 + k];
        acc[r] = fmaf(fv[0], w0, fmaf(fv[1], w1, fmaf(fv[2], w2, fmaf(fv[3], w3, acc[r]))));
      }
    }
#pragma unroll
    for (int r = 0; r < 16; ++r) part[(wv * 16 + r) * 64 + d] = acc[r];
  }
  __syncthreads();

  // phase D: r2 = y1 + o2 + b2 ; h2 = LN2 ; partial pool
  {
    float pool = 0.f;
    const float bd2 = b2[d], gd = g2[d], bd = be2[d];
#pragma unroll
    for (int rr = 0; rr < 4; ++rr) {
      const int row = wv * 4 + rr;
      const float o2 = part[row * 64 + d] + part[(16 + row) * 64 + d] +
                       part[(32 + row) * 64 + d] + part[(48 + row) * 64 + d] + bd2;
      const float rv = yr[row * 68 + d] + o2;
      const float mu = wred_sum(rv) * (1.f / 64.f);
      const float dd = rv - mu;
      const float var = wred_sum(dd * dd) * (1.f / 64.f);
      pool += dd * rsqrtf(var + 1e-5f) * gd + bd;
    }
    pw[wv * 64 + d] = pool;
  }
  __syncthreads();
  if (t < 64) pp[(size_t)blockIdx.x * 64 + t] = pw[t] + pw[64 + t] + pw[128 + t] + pw[192 + t];
}

// ---- 5: reduce pool partials + classifier -> logits ----
__global__ __launch_bounds__(64) void r7_cls(const float* __restrict__ pp,
                                             const float* __restrict__ Wc1,
                                             const float* __restrict__ bc1,
                                             const float* __restrict__ Wc2,
                                             const float* __restrict__ bc2,
                                             float* __restrict__ outp) {
  const int b = blockIdx.x, d = threadIdx.x;
  float po = 0.f;
  for (int i = 0; i < 64; ++i) po += pp[(size_t)(b * 64 + i) * 64 + d];
  po *= (1.f / 1024.f);
  float acc = bc1[d];
  for (int k = 0; k < 64; ++k) acc = fmaf(__shfl(po, k), Wc1[(size_t)k * 64 + d], acc);
  const float t1 = fmaxf(acc, 0.f);
  const float l0 = wred_sum(t1 * Wc2[(size_t)d * 2 + 0]);
  const float l1 = wred_sum(t1 * Wc2[(size_t)d * 2 + 1]);
  if (d == 0) {
    outp[b * 2 + 0] = l0 + bc2[0];
    outp[b * 2 + 1] = l1 + bc2[1];
  }
}

extern "C" void kernel_launch(void* const* d_in, const int* in_sizes, int n_in,
                              void* d_out, int out_size, void* d_ws, size_t ws_size,
                              hipStream_t stream) {
  (void)in_sizes; (void)n_in; (void)out_size; (void)ws_size;
  const float* x     = (const float*)d_in[0];
  const float* W_in  = (const float*)d_in[1];
  const float* b_in  = (const float*)d_in[2];
  const float* W_qkv = (const float*)d_in[3];
  const float* b_qkv = (const float*)d_in[4];
  const float* W_o   = (const float*)d_in[5];
  const float* b_o   = (const float*)d_in[6];
  const float* g1    = (const float*)d_in[7];
  const float* be1   = (const float*)d_in[8];
  const float* W1    = (const float*)d_in[9];
  const float* b1    = (const float*)d_in[10];
  const float* W2    = (const float*)d_in[11];
  const float* b2    = (const float*)d_in[12];
  const float* g2    = (const float*)d_in[13];
  const float* be2   = (const float*)d_in[14];
  const float* Wc1   = (const float*)d_in[15];
  const float* bc1   = (const float*)d_in[16];
  const float* Wc2   = (const float*)d_in[17];
  const float* bc2   = (const float*)d_in[18];

  char* ws = (char*)d_ws;
  const size_t SZF = (size_t)65536 * 64 * 4;       // 16.78 MB
  const size_t SZH = (size_t)128 * 1024 * 32 * 2;  //  8.39 MB
  float* hf  = (float*)(ws + 0);
  u16* qH    = (u16*)(ws + SZF);
  u16* qL    = (u16*)(ws + SZF + 1 * SZH);
  u16* kH    = (u16*)(ws + SZF + 2 * SZH);
  u16* kL    = (u16*)(ws + SZF + 3 * SZH);
  u16* vtH   = (u16*)(ws + SZF + 4 * SZH);
  u16* vtL   = (u16*)(ws + SZF + 5 * SZH);
  float* ctx = (float*)(ws + SZF + 6 * SZH);
  float* pp  = (float*)(ws + 2 * SZF + 6 * SZH);   // 4096*64*4 = 1 MB

  float* outp = (float*)d_out;       // [logits 128 | attn] f32
  float* attn = outp + 128;

  r1_inproj<<<2048, 64, 0, stream>>>(x, W_in, b_in, hf);
  r2_qkv   <<<2048, 192, 0, stream>>>(hf, W_qkv, b_qkv, qH, qL, kH, kL, vtH, vtL);
  r3_fa    <<<8192, 256, 0, stream>>>(qH, qL, kH, kL, vtH, vtL, attn, ctx);
  r56_ln_ff<<<4096, 256, 0, stream>>>(ctx, W_o, b_o, hf, g1, be1, W1, b1, W2, b2, g2, be2, pp);
  r7_cls   <<<64, 64, 0, stream>>>(pp, Wc1, bc1, Wc2, bc2, outp);
}

// Round 12
// 483.600 us; speedup vs baseline: 3.3351x; 1.0223x over previous
//
#include <hip/hip_runtime.h>

// MotionTransformer: B=64,S=1024,F=136,D=64,H=2,DH=32,DFF=256,C=2
// out (f32): [logits(128) | attn(134217728)].
// ROUND 12: fa at 8 waves/block (32 waves/CU) + XCD-aware block swizzle.

typedef unsigned short u16;
typedef short bf16x8 __attribute__((ext_vector_type(8)));
typedef float f32x4 __attribute__((ext_vector_type(4)));

#define DEVI __device__ __forceinline__
#define MFMA __builtin_amdgcn_mfma_f32_16x16x32_bf16

DEVI u16 f2bf(float f) {
  union { float f; unsigned u; } v; v.f = f;
  unsigned r = v.u + 0x7FFFu + ((v.u >> 16) & 1u);
  return (u16)(r >> 16);
}
DEVI float bf2f(u16 h) {
  union { unsigned u; float f; } v; v.u = ((unsigned)h) << 16;
  return v.f;
}
DEVI float wred_sum(float v) {
#pragma unroll
  for (int off = 32; off; off >>= 1) v += __shfl_xor(v, off);
  return v;
}

// ---- 1: h = x@W_in + b_in + PE. 32 rows/block, 64 thr ----
__global__ __launch_bounds__(64) void r1_inproj(const float* __restrict__ x,
                                                const float* __restrict__ Win,
                                                const float* __restrict__ bin,
                                                float* __restrict__ hf) {
  __shared__ float xs[32][140];
  const int r0 = blockIdx.x * 32, d = threadIdx.x;
  for (int e = d; e < 32 * 136; e += 64) {
    int r = e / 136, k = e - r * 136;
    xs[r][k] = x[(size_t)(r0 + r) * 136 + k];
  }
  __syncthreads();
  float acc[32];
#pragma unroll
  for (int r = 0; r < 32; ++r) acc[r] = 0.f;
  for (int k = 0; k < 136; k += 4) {
    float w0 = Win[(size_t)k * 64 + d];
    float w1 = Win[(size_t)(k + 1) * 64 + d];
    float w2 = Win[(size_t)(k + 2) * 64 + d];
    float w3 = Win[(size_t)(k + 3) * 64 + d];
#pragma unroll
    for (int r = 0; r < 32; ++r) {
      f32x4 xv = *(const f32x4*)&xs[r][k];
      acc[r] = fmaf(xv[0], w0, fmaf(xv[1], w1, fmaf(xv[2], w2, fmaf(xv[3], w3, acc[r]))));
    }
  }
  const float bcol = bin[d];
  const int m = d >> 1;
  const float freq = __expf((float)(2 * m) * -0.14391156831212787f); // -ln(1e4)/64
  const int s0 = r0 & 1023;
#pragma unroll
  for (int r = 0; r < 32; ++r) {
    const float ang = (float)(s0 + r) * freq;
    const float pe = (d & 1) ? cosf(ang) : sinf(ang);
    hf[(size_t)(r0 + r) * 64 + d] = acc[r] + bcol + pe;
  }
}

// ---- 2: qkv -> qH/qL,kH/kL [bh][s][32] ; vtH/vtL [bh][32][1024] (LDS transpose) ----
__global__ __launch_bounds__(192) void r2_qkv(const float* __restrict__ hf,
                                              const float* __restrict__ Wq,
                                              const float* __restrict__ bq,
                                              u16* __restrict__ qH, u16* __restrict__ qL,
                                              u16* __restrict__ kH, u16* __restrict__ kL,
                                              u16* __restrict__ vtH, u16* __restrict__ vtL) {
  __shared__ float hr[32][68];
  __shared__ u16 vbH[64][40];
  __shared__ u16 vbL[64][40];
  const int r0 = blockIdx.x * 32, t = threadIdx.x;
  for (int e = t; e < 2048; e += 192) {
    int r = e >> 6, k = e & 63;
    hr[r][k] = hf[(size_t)(r0 + r) * 64 + k];
  }
  __syncthreads();
  float acc[32];
  const float bias = bq[t];
#pragma unroll
  for (int r = 0; r < 32; ++r) acc[r] = bias;
  for (int k = 0; k < 64; k += 4) {
    float w0 = Wq[(size_t)k * 192 + t];
    float w1 = Wq[(size_t)(k + 1) * 192 + t];
    float w2 = Wq[(size_t)(k + 2) * 192 + t];
    float w3 = Wq[(size_t)(k + 3) * 192 + t];
#pragma unroll
    for (int r = 0; r < 32; ++r) {
      f32x4 hv = *(const f32x4*)&hr[r][k];
      acc[r] = fmaf(hv[0], w0, fmaf(hv[1], w1, fmaf(hv[2], w2, fmaf(hv[3], w3, acc[r]))));
    }
  }
  const int which = t >> 6, c = t & 63, h = c >> 5, dh = c & 31;
  const int b = r0 >> 10, s0 = r0 & 1023;
  const size_t bh = (size_t)(b * 2 + h);
#pragma unroll
  for (int r = 0; r < 32; ++r) {
    const int s = s0 + r;
    u16 hi = f2bf(acc[r]);
    u16 lo = f2bf(acc[r] - bf2f(hi));
    if (which == 0)      { qH[(bh * 1024 + s) * 32 + dh] = hi; qL[(bh * 1024 + s) * 32 + dh] = lo; }
    else if (which == 1) { kH[(bh * 1024 + s) * 32 + dh] = hi; kL[(bh * 1024 + s) * 32 + dh] = lo; }
    else                 { vbH[c][r] = hi; vbL[c][r] = lo; }
  }
  __syncthreads();
  if (t < 128) {
    const int hh = (t & 63) >> 5, dh2 = t & 31;
    const size_t vb = ((size_t)(b * 2 + hh) * 32 + dh2) * 1024 + s0;
    const u16* src = (t < 64) ? &vbH[(t & 63)][0] : &vbL[(t & 63)][0];
    u16* dst = (t < 64) ? vtH : vtL;
#pragma unroll
    for (int i = 0; i < 2; ++i) {
      bf16x8 v = *(const bf16x8*)&src[i * 16];
      bf16x8 w = *(const bf16x8*)&src[i * 16 + 8];
      *(bf16x8*)&dst[vb + i * 16] = v;
      *(bf16x8*)&dst[vb + i * 16 + 8] = w;
    }
  }
}

// ---- 3: FUSED attention, 8 waves/block, XCD-swizzled ----
__global__ __launch_bounds__(512, 4) void r3_fa(const u16* __restrict__ qH, const u16* __restrict__ qL,
                                                const u16* __restrict__ kH, const u16* __restrict__ kL,
                                                const u16* __restrict__ vtH, const u16* __restrict__ vtL,
                                                float* __restrict__ attn, float* __restrict__ ctx) {
  __shared__ __align__(16) char smem[33792];
  u16* pb = (u16*)smem;                        // [16][1024] bf16 P, swizzled (32 KB)
  float* redm = (float*)(smem + 32768);        // [8][16]
  float* reds = (float*)(smem + 33280);        // [8][16]
  float* part = (float*)smem;                  // [8][16][32] aliased over pb after PV

  // XCD swizzle: 8192 blocks, 8 XCDs -> same-bh q-tiles on one XCD
  const int bid = blockIdx.x;
  const int wid = (bid & 7) * 1024 + (bid >> 3);
  const int bh = wid >> 6, qt = wid & 63;
  const int t = threadIdx.x, lane = t & 63, wv = t >> 6;   // wv 0..7
  const int fr = lane & 15, rg = lane >> 4, koff = rg * 8;
  const int i0 = qt * 16;
  const float scale = 0.17677669529663687f; // 1/sqrt(32)

  const size_t qoff = ((size_t)bh * 1024 + i0 + fr) * 32 + koff;
  bf16x8 aqh = *(const bf16x8*)&qH[qoff];
  bf16x8 aql = *(const bf16x8*)&qL[qoff];

  // QK^T: wave wv owns k-cols [wv*128, wv*128+128)
  f32x4 s[8];
#pragma unroll
  for (int jl = 0; jl < 8; ++jl) {
    const int jt = wv * 8 + jl;
    const size_t kof = ((size_t)bh * 1024 + jt * 16 + fr) * 32 + koff;
    bf16x8 bkh = *(const bf16x8*)&kH[kof];
    bf16x8 bkl = *(const bf16x8*)&kL[kof];
    f32x4 a = {};
    a = MFMA(aqh, bkh, a, 0, 0, 0);
    a = MFMA(aqh, bkl, a, 0, 0, 0);
    a = MFMA(aql, bkh, a, 0, 0, 0);
#pragma unroll
    for (int r = 0; r < 4; ++r) s[jl][r] = a[r] * scale;
  }

  // split-k softmax across 8 waves
  float m4[4];
#pragma unroll
  for (int r = 0; r < 4; ++r) m4[r] = s[0][r];
#pragma unroll
  for (int jl = 1; jl < 8; ++jl)
#pragma unroll
    for (int r = 0; r < 4; ++r) m4[r] = fmaxf(m4[r], s[jl][r]);
#pragma unroll
  for (int off = 1; off < 16; off <<= 1)
#pragma unroll
    for (int r = 0; r < 4; ++r) m4[r] = fmaxf(m4[r], __shfl_xor(m4[r], off));
  if (fr == 0) {
#pragma unroll
    for (int r = 0; r < 4; ++r) redm[wv * 16 + rg * 4 + r] = m4[r];
  }
  __syncthreads();
  float mg[4];
#pragma unroll
  for (int r = 0; r < 4; ++r) {
    const int row = rg * 4 + r;
    float m = redm[row];
#pragma unroll
    for (int w = 1; w < 8; ++w) m = fmaxf(m, redm[w * 16 + row]);
    mg[r] = m;
  }
  float s4[4] = {0.f, 0.f, 0.f, 0.f};
#pragma unroll
  for (int jl = 0; jl < 8; ++jl)
#pragma unroll
    for (int r = 0; r < 4; ++r) { s[jl][r] = __expf(s[jl][r] - mg[r]); s4[r] += s[jl][r]; }
#pragma unroll
  for (int off = 1; off < 16; off <<= 1)
#pragma unroll
    for (int r = 0; r < 4; ++r) s4[r] += __shfl_xor(s4[r], off);
  if (fr == 0) {
#pragma unroll
    for (int r = 0; r < 4; ++r) reds[wv * 16 + rg * 4 + r] = s4[r];
  }
  __syncthreads();
  float inv[4];
#pragma unroll
  for (int r = 0; r < 4; ++r) {
    const int row = rg * 4 + r;
    float ssum = reds[row];
#pragma unroll
    for (int w = 1; w < 8; ++w) ssum += reds[w * 16 + row];
    inv[r] = 1.f / ssum;
  }

  // P -> bf16 LDS (swizzled: col ^ ((row>>2)<<4))
#pragma unroll
  for (int r = 0; r < 4; ++r) {
    const int row = rg * 4 + r;
    const int sw = rg << 4;
    const int rb = row * 1024;
#pragma unroll
    for (int jl = 0; jl < 8; ++jl) {
      const int col = (wv * 8 + jl) * 16 + fr;
      pb[rb + (col ^ sw)] = f2bf(s[jl][r] * inv[r]);
    }
  }
  __syncthreads();

  // coalesced nt attn write from LDS: thread t -> row t>>5, cols (t&31)*8 + 256c
  {
    const int row = t >> 5, x32 = t & 31;
    const int sw = (row >> 2) << 4;
    const size_t gb = ((size_t)bh * 1024 + i0 + row) * 1024;
#pragma unroll
    for (int c = 0; c < 4; ++c) {
      const int col = x32 * 8 + 256 * c;
      bf16x8 v = *(const bf16x8*)&pb[row * 1024 + (col ^ sw)];
      f32x4 lo, hi;
#pragma unroll
      for (int i = 0; i < 4; ++i) { lo[i] = bf2f((u16)v[i]); hi[i] = bf2f((u16)v[4 + i]); }
      __builtin_nontemporal_store(lo, (f32x4*)&attn[gb + col]);
      __builtin_nontemporal_store(hi, (f32x4*)&attn[gb + col + 4]);
    }
  }

  // PV: wave wv handles k-tiles wv*4..wv*4+3
  const int sw2 = (fr >> 2) << 4;
  f32x4 acc2[2] = {};
#pragma unroll
  for (int i = 0; i < 4; ++i) {
    const int kt = wv * 4 + i;
    const int cb = kt * 32 + rg * 8;
    bf16x8 ph = *(const bf16x8*)&pb[fr * 1024 + (cb ^ sw2)];
#pragma unroll
    for (int nb = 0; nb < 2; ++nb) {
      const size_t vo = ((size_t)bh * 32 + nb * 16 + fr) * 1024 + cb;
      bf16x8 vh = *(const bf16x8*)&vtH[vo];
      bf16x8 vl = *(const bf16x8*)&vtL[vo];
      acc2[nb] = MFMA(ph, vh, acc2[nb], 0, 0, 0);
      acc2[nb] = MFMA(ph, vl, acc2[nb], 0, 0, 0);
    }
  }
  __syncthreads();   // all pb reads done; part may overwrite
#pragma unroll
  for (int nb = 0; nb < 2; ++nb)
#pragma unroll
    for (int r = 0; r < 4; ++r)
      part[(wv * 16 + rg * 4 + r) * 32 + nb * 16 + fr] = acc2[nb][r];
  __syncthreads();
  const int b = bh >> 1, h = bh & 1;
  {
    const int row = t >> 5, dh = t & 31;
    float v = part[(row) * 32 + dh];
#pragma unroll
    for (int w = 1; w < 8; ++w) v += part[(w * 16 + row) * 32 + dh];
    ctx[((size_t)b * 1024 + i0 + row) * 64 + h * 32 + dh] = v;
  }
}

// ---- 4: FUSED ln1 + FF + ln2 + partial pool. 16 rows/block, 256 thr ----
__global__ __launch_bounds__(256) void r56_ln_ff(const float* __restrict__ ctx,
                                                 const float* __restrict__ Wo,
                                                 const float* __restrict__ bo,
                                                 const float* __restrict__ hf,
                                                 const float* __restrict__ g1,
                                                 const float* __restrict__ be1,
                                                 const float* __restrict__ W1,
                                                 const float* __restrict__ b1,
                                                 const float* __restrict__ W2,
                                                 const float* __restrict__ b2,
                                                 const float* __restrict__ g2,
                                                 const float* __restrict__ be2,
                                                 float* __restrict__ pp) {
  __shared__ __align__(16) char smem[38656];
  float* yr   = (float*)smem;                 // [16][68]
  float* fr   = (float*)(smem + 4352);        // [16][264]
  float* part = (float*)(smem + 21248);       // [4][16][64]
  float* cr   = (float*)(smem + 4352);        // [16][68] phase A
  float* wo   = (float*)(smem + 8704);        // [64][64] phase A
  float* pw   = (float*)(smem + 37632);       // [4][64]
  const int r0 = blockIdx.x * 16;
  const int t = threadIdx.x, d = t & 63, wv = t >> 6;

  for (int e = t; e < 1024; e += 256) cr[(e >> 6) * 68 + (e & 63)] = ctx[(size_t)(r0 + (e >> 6)) * 64 + (e & 63)];
  for (int e = t; e < 4096; e += 256) wo[e] = Wo[e];
  __syncthreads();

  {
    float acc[4];
    const float bias = bo[d];
#pragma unroll
    for (int r = 0; r < 4; ++r) acc[r] = bias;
    for (int k = 0; k < 64; ++k) {
      const float w = wo[k * 64 + d];
#pragma unroll
      for (int r = 0; r < 4; ++r) acc[r] = fmaf(cr[(wv * 4 + r) * 68 + k], w, acc[r]);
    }
    const float gd = g1[d], bd = be1[d];
#pragma unroll
    for (int r = 0; r < 4; ++r) {
      const int row = wv * 4 + r;
      const float rv = hf[(size_t)(r0 + row) * 64 + d] + acc[r];
      const float mu = wred_sum(rv) * (1.f / 64.f);
      const float dd = rv - mu;
      const float var = wred_sum(dd * dd) * (1.f / 64.f);
      yr[row * 68 + d] = dd * rsqrtf(var + 1e-5f) * gd + bd;
    }
  }
  __syncthreads();

  {
    float acc[16];
    const float bias = b1[t];
#pragma unroll
    for (int r = 0; r < 16; ++r) acc[r] = bias;
    for (int k = 0; k < 64; k += 4) {
      float w0 = W1[(size_t)k * 256 + t];
      float w1 = W1[(size_t)(k + 1) * 256 + t];
      float w2 = W1[(size_t)(k + 2) * 256 + t];
      float w3 = W1[(size_t)(k + 3) * 256 + t];
#pragma unroll
      for (int r = 0; r < 16; ++r) {
        f32x4 yv = *(const f32x4*)&yr[r * 68 + k];
        acc[r] = fmaf(yv[0], w0, fmaf(yv[1], w1, fmaf(yv[2], w2, fmaf(yv[3], w3, acc[r]))));
      }
    }
#pragma unroll
    for (int r = 0; r < 16; ++r) fr[r * 264 + t] = fmaxf(acc[r], 0.f);
  }
  __syncthreads();

  {
    float acc[16];
#pragma unroll
    for (int r = 0; r < 16; ++r) acc[r] = 0.f;
    for (int kk = 0; kk < 64; kk += 4) {
      const int k = wv * 64 + kk;
      float w0 = W2[(size_t)k * 64 + d];
      float w1 = W2[(size_t)(k + 1) * 64 + d];
      float w2 = W2[(size_t)(k + 2) * 64 + d];
      float w3 = W2[(size_t)(k + 3) * 64 + d];
#pragma unroll
      for (int r = 0; r < 16; ++r) {
        f32x4 fv = *(const f32x4*)&fr[r * 264 + k];
        acc[r] = fmaf(fv[0], w0, fmaf(fv[1], w1, fmaf(fv[2], w2, fmaf(fv[3], w3, acc[r]))));
      }
    }
#pragma unroll
    for (int r = 0; r < 16; ++r) part[(wv * 16 + r) * 64 + d] = acc[r];
  }
  __syncthreads();

  {
    float pool = 0.f;
    const float bd2 = b2[d], gd = g2[d], bd = be2[d];
#pragma unroll
    for (int rr = 0; rr < 4; ++rr) {
      const int row = wv * 4 + rr;
      const float o2 = part[row * 64 + d] + part[(16 + row) * 64 + d] +
                       part[(32 + row) * 64 + d] + part[(48 + row) * 64 + d] + bd2;
      const float rv = yr[row * 68 + d] + o2;
      const float mu = wred_sum(rv) * (1.f / 64.f);
      const float dd = rv - mu;
      const float var = wred_sum(dd * dd) * (1.f / 64.f);
      pool += dd * rsqrtf(var + 1e-5f) * gd + bd;
    }
    pw[wv * 64 + d] = pool;
  }
  __syncthreads();
  if (t < 64) pp[(size_t)blockIdx.x * 64 + t] = pw[t] + pw[64 + t] + pw[128 + t] + pw[192 + t];
}

// ---- 5: reduce pool partials + classifier -> logits ----
__global__ __launch_bounds__(64) void r7_cls(const float* __restrict__ pp,
                                             const float* __restrict__ Wc1,
                                             const float* __restrict__ bc1,
                                             const float* __restrict__ Wc2,
                                             const float* __restrict__ bc2,
                                             float* __restrict__ outp) {
  const int b = blockIdx.x, d = threadIdx.x;
  float po = 0.f;
  for (int i = 0; i < 64; ++i) po += pp[(size_t)(b * 64 + i) * 64 + d];
  po *= (1.f / 1024.f);
  float acc = bc1[d];
  for (int k = 0; k < 64; ++k) acc = fmaf(__shfl(po, k), Wc1[(size_t)k * 64 + d], acc);
  const float t1 = fmaxf(acc, 0.f);
  const float l0 = wred_sum(t1 * Wc2[(size_t)d * 2 + 0]);
  const float l1 = wred_sum(t1 * Wc2[(size_t)d * 2 + 1]);
  if (d == 0) {
    outp[b * 2 + 0] = l0 + bc2[0];
    outp[b * 2 + 1] = l1 + bc2[1];
  }
}

extern "C" void kernel_launch(void* const* d_in, const int* in_sizes, int n_in,
                              void* d_out, int out_size, void* d_ws, size_t ws_size,
                              hipStream_t stream) {
  (void)in_sizes; (void)n_in; (void)out_size; (void)ws_size;
  const float* x     = (const float*)d_in[0];
  const float* W_in  = (const float*)d_in[1];
  const float* b_in  = (const float*)d_in[2];
  const float* W_qkv = (const float*)d_in[3];
  const float* b_qkv = (const float*)d_in[4];
  const float* W_o   = (const float*)d_in[5];
  const float* b_o   = (const float*)d_in[6];
  const float* g1    = (const float*)d_in[7];
  const float* be1   = (const float*)d_in[8];
  const float* W1    = (const float*)d_in[9];
  const float* b1    = (const float*)d_in[10];
  const float* W2    = (const float*)d_in[11];
  const float* b2    = (const float*)d_in[12];
  const float* g2    = (const float*)d_in[13];
  const float* be2   = (const float*)d_in[14];
  const float* Wc1   = (const float*)d_in[15];
  const float* bc1   = (const float*)d_in[16];
  const float* Wc2   = (const float*)d_in[17];
  const float* bc2   = (const float*)d_in[18];

  char* ws = (char*)d_ws;
  const size_t SZF = (size_t)65536 * 64 * 4;       // 16.78 MB
  const size_t SZH = (size_t)128 * 1024 * 32 * 2;  //  8.39 MB
  float* hf  = (float*)(ws + 0);
  u16* qH    = (u16*)(ws + SZF);
  u16* qL    = (u16*)(ws + SZF + 1 * SZH);
  u16* kH    = (u16*)(ws + SZF + 2 * SZH);
  u16* kL    = (u16*)(ws + SZF + 3 * SZH);
  u16* vtH   = (u16*)(ws + SZF + 4 * SZH);
  u16* vtL   = (u16*)(ws + SZF + 5 * SZH);
  float* ctx = (float*)(ws + SZF + 6 * SZH);
  float* pp  = (float*)(ws + 2 * SZF + 6 * SZH);   // 1 MB

  float* outp = (float*)d_out;       // [logits 128 | attn] f32
  float* attn = outp + 128;

  r1_inproj<<<2048, 64, 0, stream>>>(x, W_in, b_in, hf);
  r2_qkv   <<<2048, 192, 0, stream>>>(hf, W_qkv, b_qkv, qH, qL, kH, kL, vtH, vtL);
  r3_fa    <<<8192, 512, 0, stream>>>(qH, qL, kH, kL, vtH, vtL, attn, ctx);
  r56_ln_ff<<<4096, 256, 0, stream>>>(ctx, W_o, b_o, hf, g1, be1, W1, b1, W2, b2, g2, be2, pp);
  r7_cls   <<<64, 64, 0, stream>>>(pp, Wc1, bc1, Wc2, bc2, outp);
}